// Round 9
// baseline (261.267 us; speedup 1.0000x reference)
//
#include <hip/hip_runtime.h>

// ---- constants for B=4, S=2048, D=768, H=12, HD=64 ----
#define BB 4
#define SS 2048
#define DD 768
#define HH 12
#define HDD 64
#define BS (BB*SS)            // 8192 rows
#define NQKV (3*DD)           // 2304
#define NEL (BS*DD)           // 6291456

typedef __attribute__((ext_vector_type(8))) __bf16 bf16x8;
typedef __attribute__((ext_vector_type(4))) float fx4;
typedef __attribute__((ext_vector_type(4))) int   ix4;

#define MFMA16(a,b,c) __builtin_amdgcn_mfma_f32_16x16x32_bf16((a),(b),(c),0,0,0)

// async global->LDS, 16B per lane, lane-linear dest (wave-uniform base + lane*16)
#define GLLDS(g, l) __builtin_amdgcn_global_load_lds( \
    (const __attribute__((address_space(1))) void*)(g), \
    (__attribute__((address_space(3))) void*)(l), 16, 0, 0)

__device__ __forceinline__ unsigned short f2bf(float f) {
  unsigned u = __builtin_bit_cast(unsigned, f);
  u = (u + 0x7FFFu + ((u >> 16) & 1u)) >> 16;
  return (unsigned short)u;
}
// pack two fp32 -> bf16 pair
__device__ __forceinline__ unsigned pkbf(float a, float b) {
  unsigned ua = __builtin_bit_cast(unsigned, a);
  unsigned ub = __builtin_bit_cast(unsigned, b);
  return ((ua + 0x8000u) >> 16) | ((ub + 0x8000u) & 0xFFFF0000u);
}
// hardware packed fp32->bf16 (RNE), 1 instr for 2 elems
__device__ __forceinline__ unsigned cvtpk(float a, float b) {
  unsigned r;
  asm("v_cvt_pk_bf16_f32 %0, %1, %2" : "=v"(r) : "v"(a), "v"(b));
  return r;
}
__device__ __forceinline__ float ex2(float x) { return __builtin_amdgcn_exp2f(x); }

// ---- fused prep: pack ctx->bf16 + transpose both weight matrices ----
#define PREP_PACK   6144
#define PREP_TQKV   1728   // 72 x 24 tiles
#define PREP_TPROJ  576    // 24 x 24 tiles
__global__ __launch_bounds__(256) void prep_k(const float* __restrict__ ctx,
                                              unsigned short* __restrict__ Xbf,
                                              const float* __restrict__ wqkv,
                                              unsigned short* __restrict__ WqkvT,
                                              const float* __restrict__ wproj,
                                              unsigned short* __restrict__ WprojT) {
  __shared__ unsigned short t[32][33];
  const int bid = blockIdx.x;
  const int tid = threadIdx.x;
  if (bid < PREP_PACK) {
    int i = bid * 256 + tid;
    float4 v = ((const float4*)ctx)[i];
    ((uint2*)Xbf)[i] = make_uint2(pkbf(v.x, v.y), pkbf(v.z, v.w));
    return;
  }
  const float* w; unsigned short* wT; int K, N, bx, by;
  if (bid < PREP_PACK + PREP_TQKV) {
    int tix = bid - PREP_PACK;
    w = wqkv; wT = WqkvT; K = DD; N = NQKV;
    bx = tix % 72; by = tix / 72;
  } else {
    int tix = bid - PREP_PACK - PREP_TQKV;
    w = wproj; wT = WprojT; K = DD; N = DD;
    bx = tix % 24; by = tix / 24;
  }
  int n0 = bx * 32, k0 = by * 32;
  int tx = tid & 31, ty = tid >> 5;
#pragma unroll
  for (int r = ty; r < 32; r += 8)
    t[tx][r] = f2bf(w[(size_t)(k0 + r) * N + n0 + tx]);
  __syncthreads();
#pragma unroll
  for (int r = ty; r < 32; r += 8)
    wT[(size_t)(n0 + r) * K + k0 + tx] = t[r][tx];
}

// XCD-aware block swizzle (requires nwg % 8 == 0; both GEMM grids satisfy)
__device__ __forceinline__ void xcd_swz(int gx, int* bx, int* by) {
  int nwg = gx * gridDim.y;
  int flat = blockIdx.y * gx + blockIdx.x;
  int cpx = nwg >> 3;
  int swz = (flat & 7) * cpx + (flat >> 3);
  *bx = swz % gx;
  *by = swz / gx;
}

// ==== QKV GEMM: C^T[feature][seq] = Wt(2304x768) x X(8192x768)^T ====
// 128x128 tile, BK=32, 3-buffer GLLDS ring with raw s_barrier + COUNTED vmcnt:
// iter t issues tile t+2; waits vmcnt(4) (tile t complete, t+1/t+2 in flight).
__global__ __launch_bounds__(256) void gemm_qkv_k(const unsigned short* __restrict__ Wt,
                                                  const unsigned short* __restrict__ X,
                                                  unsigned short* __restrict__ Qo,
                                                  unsigned short* __restrict__ Ko,
                                                  unsigned short* __restrict__ Vto) {
  __shared__ unsigned short As[3 * 128 * 32];   // 3 x 8KB ring
  __shared__ unsigned short Bs[3 * 128 * 32];
  const int tid = threadIdx.x;
  const int w = tid >> 6, lane = tid & 63, quad = lane >> 4, l16 = lane & 15;
  int bx, by; xcd_swz(gridDim.x, &bx, &by);
  const int m0 = by << 7;   // feature
  const int n0 = bx << 7;   // seq row
  const int wm = (w & 1) * 64, wn = (w >> 1) * 64;
  fx4 acc[4][4];
#pragma unroll
  for (int i = 0; i < 4; ++i)
#pragma unroll
    for (int c = 0; c < 4; ++c) acc[i][c] = (fx4){0.f, 0.f, 0.f, 0.f};

  const int c0 = tid, c1 = 256 + tid;
  const unsigned short* Ag0 = Wt + (size_t)(m0 + (c0 >> 2)) * DD + (c0 & 3) * 8;
  const unsigned short* Ag1 = Wt + (size_t)(m0 + (c1 >> 2)) * DD + (c1 & 3) * 8;
  const unsigned short* Bg0 = X + (size_t)(n0 + (c0 >> 2)) * DD + (c0 & 3) * 8;
  const unsigned short* Bg1 = X + (size_t)(n0 + (c1 >> 2)) * DD + (c1 & 3) * 8;
  const int wb = w * 1024;   // wave's lane-linear LDS byte base

  // prologue: tiles 0,1 -> bufs 0,1 (FIFO order: t0's 4 loads oldest)
  GLLDS(Ag0, (char*)As + wb);
  GLLDS(Ag1, (char*)As + 4096 + wb);
  GLLDS(Bg0, (char*)Bs + wb);
  GLLDS(Bg1, (char*)Bs + 4096 + wb);
  GLLDS(Ag0 + 32, (char*)As + 8192 + wb);
  GLLDS(Ag1 + 32, (char*)As + 8192 + 4096 + wb);
  GLLDS(Bg0 + 32, (char*)Bs + 8192 + wb);
  GLLDS(Bg1 + 32, (char*)Bs + 8192 + 4096 + wb);
  int cur = 0, wr = 2;

  for (int k0 = 0; k0 < DD; k0 += 32) {
    if (k0 + 32 < DD) {
      asm volatile("s_waitcnt vmcnt(4)" ::: "memory");   // oldest tile landed
    } else {
      asm volatile("s_waitcnt vmcnt(0)" ::: "memory");   // last tile: drain
    }
    __builtin_amdgcn_s_barrier();        // raw: no compiler waitcnt drain
    __builtin_amdgcn_sched_barrier(0);   // pin LDS reads below barrier
    if (k0 + 64 < DD) {                  // issue tile t+2 into buf last read at t-1
      GLLDS(Ag0 + k0 + 64, (char*)As + wr * 8192 + wb);
      GLLDS(Ag1 + k0 + 64, (char*)As + wr * 8192 + 4096 + wb);
      GLLDS(Bg0 + k0 + 64, (char*)Bs + wr * 8192 + wb);
      GLLDS(Bg1 + k0 + 64, (char*)Bs + wr * 8192 + 4096 + wb);
    }
    const unsigned short* Asc = As + cur * 4096;
    const unsigned short* Bsc = Bs + cur * 4096;
    bf16x8 af[4], bf[4];
#pragma unroll
    for (int i = 0; i < 4; ++i) af[i] = *(const bf16x8*)&Asc[(wm + i * 16 + l16) * 32 + quad * 8];
#pragma unroll
    for (int c = 0; c < 4; ++c) bf[c] = *(const bf16x8*)&Bsc[(wn + c * 16 + l16) * 32 + quad * 8];
#pragma unroll
    for (int i = 0; i < 4; ++i)
#pragma unroll
      for (int c = 0; c < 4; ++c) acc[i][c] = MFMA16(af[i], bf[c], acc[i][c]);
    cur = (cur == 2) ? 0 : cur + 1;
    wr  = (wr == 2) ? 0 : wr + 1;
  }

  const int which = m0 / DD;  // block-uniform: 0=Q 1=K 2=V (768 = 6*128, no straddle)
#pragma unroll
  for (int i = 0; i < 4; ++i) {
    int fb = m0 + wm + i * 16 + quad * 4;
    int d = fb - which * DD;
    int h = d >> 6, hd = d & 63;
#pragma unroll
    for (int c = 0; c < 4; ++c) {
      int srow = n0 + wn + c * 16 + l16;
      int b = srow >> 11, s = srow & (SS - 1);
      if (which == 0) {
        uint2 v = make_uint2(pkbf(acc[i][c][0], acc[i][c][1]), pkbf(acc[i][c][2], acc[i][c][3]));
        *(uint2*)&Qo[((size_t)(b * HH + h) * SS + s) * HDD + hd] = v;
      } else if (which == 1) {
        uint2 v = make_uint2(pkbf(acc[i][c][0], acc[i][c][1]), pkbf(acc[i][c][2], acc[i][c][3]));
        *(uint2*)&Ko[((size_t)(b * HH + h) * SS + s) * HDD + hd] = v;
      } else {
#pragma unroll
        for (int r = 0; r < 4; ++r)
          Vto[((size_t)(b * HH + h) * HDD + hd + r) * SS + s] = f2bf(acc[i][c][r]);
      }
    }
  }
}

// ==== proj GEMM: C^T[feat][seq] = WprojT(768x768) x Ao(8192x768)^T ====
// Same 3-buffer counted-vmcnt ring. Epilogue: + b_proj + residual(ctx), fp32 out.
__global__ __launch_bounds__(256) void gemm_proj_k(const unsigned short* __restrict__ Wt,
                                                   const unsigned short* __restrict__ X,
                                                   const float* __restrict__ ctx,
                                                   const float* __restrict__ bproj,
                                                   float* __restrict__ xf) {
  __shared__ unsigned short As[3 * 128 * 32];
  __shared__ unsigned short Bs[3 * 128 * 32];
  const int tid = threadIdx.x;
  const int w = tid >> 6, lane = tid & 63, quad = lane >> 4, l16 = lane & 15;
  int bx, by; xcd_swz(gridDim.x, &bx, &by);
  const int m0 = by << 7;
  const int n0 = bx << 7;
  const int wm = (w & 1) * 64, wn = (w >> 1) * 64;
  fx4 acc[4][4];
#pragma unroll
  for (int i = 0; i < 4; ++i)
#pragma unroll
    for (int c = 0; c < 4; ++c) acc[i][c] = (fx4){0.f, 0.f, 0.f, 0.f};

  const int c0 = tid, c1 = 256 + tid;
  const unsigned short* Ag0 = Wt + (size_t)(m0 + (c0 >> 2)) * DD + (c0 & 3) * 8;
  const unsigned short* Ag1 = Wt + (size_t)(m0 + (c1 >> 2)) * DD + (c1 & 3) * 8;
  const unsigned short* Bg0 = X + (size_t)(n0 + (c0 >> 2)) * DD + (c0 & 3) * 8;
  const unsigned short* Bg1 = X + (size_t)(n0 + (c1 >> 2)) * DD + (c1 & 3) * 8;
  const int wb = w * 1024;

  GLLDS(Ag0, (char*)As + wb);
  GLLDS(Ag1, (char*)As + 4096 + wb);
  GLLDS(Bg0, (char*)Bs + wb);
  GLLDS(Bg1, (char*)Bs + 4096 + wb);
  GLLDS(Ag0 + 32, (char*)As + 8192 + wb);
  GLLDS(Ag1 + 32, (char*)As + 8192 + 4096 + wb);
  GLLDS(Bg0 + 32, (char*)Bs + 8192 + wb);
  GLLDS(Bg1 + 32, (char*)Bs + 8192 + 4096 + wb);
  int cur = 0, wr = 2;

  for (int k0 = 0; k0 < DD; k0 += 32) {
    if (k0 + 32 < DD) {
      asm volatile("s_waitcnt vmcnt(4)" ::: "memory");
    } else {
      asm volatile("s_waitcnt vmcnt(0)" ::: "memory");
    }
    __builtin_amdgcn_s_barrier();
    __builtin_amdgcn_sched_barrier(0);
    if (k0 + 64 < DD) {
      GLLDS(Ag0 + k0 + 64, (char*)As + wr * 8192 + wb);
      GLLDS(Ag1 + k0 + 64, (char*)As + wr * 8192 + 4096 + wb);
      GLLDS(Bg0 + k0 + 64, (char*)Bs + wr * 8192 + wb);
      GLLDS(Bg1 + k0 + 64, (char*)Bs + wr * 8192 + 4096 + wb);
    }
    const unsigned short* Asc = As + cur * 4096;
    const unsigned short* Bsc = Bs + cur * 4096;
    bf16x8 af[4], bf[4];
#pragma unroll
    for (int i = 0; i < 4; ++i) af[i] = *(const bf16x8*)&Asc[(wm + i * 16 + l16) * 32 + quad * 8];
#pragma unroll
    for (int c = 0; c < 4; ++c) bf[c] = *(const bf16x8*)&Bsc[(wn + c * 16 + l16) * 32 + quad * 8];
#pragma unroll
    for (int i = 0; i < 4; ++i)
#pragma unroll
      for (int c = 0; c < 4; ++c) acc[i][c] = MFMA16(af[i], bf[c], acc[i][c]);
    cur = (cur == 2) ? 0 : cur + 1;
    wr  = (wr == 2) ? 0 : wr + 1;
  }

#pragma unroll
  for (int i = 0; i < 4; ++i) {
    int fb = m0 + wm + i * 16 + quad * 4;
    float4 bp = *(const float4*)&bproj[fb];
#pragma unroll
    for (int c = 0; c < 4; ++c) {
      int srow = n0 + wn + c * 16 + l16;
      float4 cx = *(const float4*)&ctx[(size_t)srow * DD + fb];
      float4 r;
      r.x = acc[i][c][0] + bp.x + cx.x;
      r.y = acc[i][c][1] + bp.y + cx.y;
      r.z = acc[i][c][2] + bp.z + cx.z;
      r.w = acc[i][c][3] + bp.w + cx.w;
      *(float4*)&xf[(size_t)srow * DD + fb] = r;
    }
  }
}

// ==== attention: S^T = K·Q^T; P stays in registers (k-permuted PV) ====
// block = 128 q-rows x one (b,h); 4 waves x 32 q-rows; 64-key tiles.
// NEW: GLLDS double-buffer, ONE raw barrier per tile. Compute phase has zero
// vmem (mask coeffs in LDS, Q in regs), so vmcnt(0) covers only the 4 staging
// DMAs issued a full compute-phase earlier (K/V L2-resident: wait ~free).
// Removes the serial ds_write phase + one barrier per tile.
__global__ __launch_bounds__(256) void attn_k(const unsigned short* __restrict__ Q,
                                              const unsigned short* __restrict__ K,
                                              const unsigned short* __restrict__ Vt,
                                              const float* __restrict__ mask,
                                              unsigned short* __restrict__ O) {
  __shared__ unsigned short Ks[2 * 64 * 64];   // 2 x 8KB, [key][dd] chunk-XOR-swizzled
  __shared__ unsigned short Vts[2 * 64 * 64];  // 2 x 8KB, [hd][key] same swizzle
  __shared__ float kaS[SS];                    // per-key softmax coeff a (8KB)
  __shared__ float kbS[SS];                    // per-key softmax coeff b (8KB)
  const int tid = threadIdx.x;
  const int w = tid >> 6, lane = tid & 63;
  const int quad = lane >> 4, l16 = lane & 15;
  const int bh = blockIdx.y;
  const int b = bh / HH, h = bh - b * HH;
  const int q0 = blockIdx.x << 7;
  const unsigned short* Qb = Q + (size_t)bh * (SS * HDD);
  const unsigned short* Kb = K + (size_t)bh * (SS * HDD);
  const unsigned short* Vtb = Vt + (size_t)bh * (SS * HDD);
  const float* mb = mask + b * SS;

  // one-time: mask -> softmax coeffs, staged to LDS
  //   p = exp2(sc*ka + kb); ka = m*0.125*log2e; kb = (m-1)*1e10*log2e
#pragma unroll
  for (int i = 0; i < 2; ++i) {
    int idx = i * 256 + tid;                        // 512 float4 per table
    float4 mv = ((const float4*)mb)[idx];
    float4 a, c;
    a.x = mv.x * 0.18033688f; a.y = mv.y * 0.18033688f;
    a.z = mv.z * 0.18033688f; a.w = mv.w * 0.18033688f;
    c.x = __builtin_fmaf(mv.x, 1.44269504e10f, -1.44269504e10f);
    c.y = __builtin_fmaf(mv.y, 1.44269504e10f, -1.44269504e10f);
    c.z = __builtin_fmaf(mv.z, 1.44269504e10f, -1.44269504e10f);
    c.w = __builtin_fmaf(mv.w, 1.44269504e10f, -1.44269504e10f);
    ((float4*)kaS)[idx] = a;
    ((float4*)kbS)[idx] = c;
  }

  // Q fragments (B-operand: n=q=l16, k=dd natural)
  bf16x8 qf[2][2];
#pragma unroll
  for (int qi = 0; qi < 2; ++qi)
#pragma unroll
    for (int f = 0; f < 2; ++f)
      qf[qi][f] = *(const bf16x8*)&Qb[(size_t)(q0 + w * 32 + qi * 16 + l16) * HDD + f * 32 + quad * 8];

  fx4 o[2][4];
#pragma unroll
  for (int qi = 0; qi < 2; ++qi)
#pragma unroll
    for (int ht = 0; ht < 4; ++ht) o[qi][ht] = (fx4){0.f, 0.f, 0.f, 0.f};
  fx4 sacc[2];
  sacc[0] = (fx4){0.f, 0.f, 0.f, 0.f};
  sacc[1] = (fx4){0.f, 0.f, 0.f, 0.f};

  // ones fragment for row-sum MFMA (A all 1.0bf16 -> D[m][q] = sum_k P[k][q])
  const ix4 one4 = (ix4){0x3F803F80, 0x3F803F80, 0x3F803F80, 0x3F803F80};
  const bf16x8 onesf = __builtin_bit_cast(bf16x8, one4);

  // staging: 512 chunks of 16B per matrix per tile; lane-linear LDS dest,
  // pre-swizzled global source: chunk c -> row r=c>>3, slot p=(c&7)^(r&7)
  const int cA = tid, cB = 256 + tid;
  const int rA = cA >> 3, pA = (cA & 7) ^ (rA & 7);
  const int rB = cB >> 3, pB = (cB & 7) ^ (rB & 7);
  const unsigned short* kSrcA = Kb + (size_t)rA * HDD + pA * 8;
  const unsigned short* kSrcB = Kb + (size_t)rB * HDD + pB * 8;
  const unsigned short* vSrcA = Vtb + (size_t)rA * SS + pA * 8;
  const unsigned short* vSrcB = Vtb + (size_t)rB * SS + pB * 8;
  const int wbA = w * 1024;          // wave's chunk-range A byte base within buffer
  const int wbB = 4096 + w * 1024;   // chunk-range B

  // prologue: tile 0 -> buf 0
  GLLDS(kSrcA, (char*)Ks + wbA);
  GLLDS(kSrcB, (char*)Ks + wbB);
  GLLDS(vSrcA, (char*)Vts + wbA);
  GLLDS(vSrcB, (char*)Vts + wbB);
  __syncthreads();   // coeff tables visible + tile 0 landed (full drain, once)
  int cur = 0;

  for (int k0 = 0; k0 < SS; k0 += 64) {
    if (k0) {
      asm volatile("s_waitcnt vmcnt(0)" ::: "memory");  // tile t landed (my wave)
      __builtin_amdgcn_s_barrier();                     // all waves' chunks visible;
                                                        // all t-1 reads of buf[cur^1] done
      __builtin_amdgcn_sched_barrier(0);                // pin LDS reads below barrier
    }
    if (k0 + 64 < SS) {
      int kn = k0 + 64;   // issue tile t+1 into the buffer last read at t-1
      GLLDS(kSrcA + (size_t)kn * HDD, (char*)Ks + (cur ^ 1) * 8192 + wbA);
      GLLDS(kSrcB + (size_t)kn * HDD, (char*)Ks + (cur ^ 1) * 8192 + wbB);
      GLLDS(vSrcA + kn, (char*)Vts + (cur ^ 1) * 8192 + wbA);
      GLLDS(vSrcB + kn, (char*)Vts + (cur ^ 1) * 8192 + wbB);
    }
    const unsigned short* Ksc = Ks + cur * 4096;
    const char* Vtsc = (const char*)Vts + cur * 8192;

    // mask coefficients from LDS (lgkmcnt only)
    float4 mqa[4], mqb[4];
#pragma unroll
    for (int kt = 0; kt < 4; ++kt) {
      mqa[kt] = *(const float4*)&kaS[k0 + kt * 16 + quad * 4];
      mqb[kt] = *(const float4*)&kbS[k0 + kt * 16 + quad * 4];
    }

    // K fragments (A-operand: m=key=l16, k=dd natural)
    bf16x8 kf[4][2];
#pragma unroll
    for (int kt = 0; kt < 4; ++kt) {
      int row = kt * 16 + l16;
      int rx = row & 7;
#pragma unroll
      for (int f = 0; f < 2; ++f)
        kf[kt][f] = *(const bf16x8*)&Ksc[row * 64 + ((f * 4 + quad) ^ rx) * 8];
    }
    // V fragments (A-operand: m=hd=l16, k-permuted: key=f*32+(j>>2)*16+quad*4+(j&3))
    bf16x8 vf[4][2];
#pragma unroll
    for (int ht = 0; ht < 4; ++ht) {
      int row = ht * 16 + l16;
      int rx = row & 7;
#pragma unroll
      for (int f = 0; f < 2; ++f) {
        int dc0 = (f * 4 + (quad >> 1)) ^ rx;
        int dc1 = (f * 4 + 2 + (quad >> 1)) ^ rx;
        uint2 lo = *(const uint2*)(Vtsc + row * 128 + dc0 * 16 + (quad & 1) * 8);
        uint2 hi = *(const uint2*)(Vtsc + row * 128 + dc1 * 16 + (quad & 1) * 8);
        ix4 vv = (ix4){(int)lo.x, (int)lo.y, (int)hi.x, (int)hi.y};
        vf[ht][f] = __builtin_bit_cast(bf16x8, vv);
      }
    }

#pragma unroll
    for (int qi = 0; qi < 2; ++qi) {
      unsigned pw[8];
#pragma unroll
      for (int kt = 0; kt < 4; ++kt) {
        fx4 s = (fx4){0.f, 0.f, 0.f, 0.f};
        s = MFMA16(kf[kt][0], qf[qi][0], s);
        s = MFMA16(kf[kt][1], qf[qi][1], s);
        const float* ma = (const float*)&mqa[kt];
        const float* mc = (const float*)&mqb[kt];
        float p0 = ex2(__builtin_fmaf(s[0], ma[0], mc[0]));
        float p1 = ex2(__builtin_fmaf(s[1], ma[1], mc[1]));
        float p2 = ex2(__builtin_fmaf(s[2], ma[2], mc[2]));
        float p3 = ex2(__builtin_fmaf(s[3], ma[3], mc[3]));
        pw[kt * 2]     = cvtpk(p0, p1);
        pw[kt * 2 + 1] = cvtpk(p2, p3);
      }
      ix4 pi0 = (ix4){(int)pw[0], (int)pw[1], (int)pw[2], (int)pw[3]};
      ix4 pi1 = (ix4){(int)pw[4], (int)pw[5], (int)pw[6], (int)pw[7]};
      bf16x8 pf0 = __builtin_bit_cast(bf16x8, pi0);
      bf16x8 pf1 = __builtin_bit_cast(bf16x8, pi1);
      // row-sum on the MFMA pipe
      sacc[qi] = MFMA16(onesf, pf0, sacc[qi]);
      sacc[qi] = MFMA16(onesf, pf1, sacc[qi]);
#pragma unroll
      for (int ht = 0; ht < 4; ++ht) {
        o[qi][ht] = MFMA16(vf[ht][0], pf0, o[qi][ht]);
        o[qi][ht] = MFMA16(vf[ht][1], pf1, o[qi][ht]);
      }
    }
    cur ^= 1;
  }

#pragma unroll
  for (int qi = 0; qi < 2; ++qi) {
    // sacc rows are all identical (ones operand): lane's col l16 sum is in any reg
    float inv = 1.f / fmaxf(sacc[qi][0], 1e-30f);
    int sq = q0 + w * 32 + qi * 16 + l16;
    unsigned short* orow = O + ((size_t)(b * SS + sq)) * DD + h * HDD;
#pragma unroll
    for (int ht = 0; ht < 4; ++ht) {
      uint2 v = make_uint2(pkbf(o[qi][ht][0] * inv, o[qi][ht][1] * inv),
                           pkbf(o[qi][ht][2] * inv, o[qi][ht][3] * inv));
      *(uint2*)&orow[ht * 16 + quad * 4] = v;
    }
  }
}

// ---- LayerNorm over D=768: one WAVE per row, 4 rows/block, no barriers ----
__global__ __launch_bounds__(256) void ln_k(const float* __restrict__ x,
                                            const float* __restrict__ gamma,
                                            const float* __restrict__ beta,
                                            float* __restrict__ out) {
  const int wv = threadIdx.x >> 6, lane = threadIdx.x & 63;
  const int row = blockIdx.x * 4 + wv;
  const float* xr = x + (size_t)row * DD;
  float4 v[3];
  float s = 0.f, ss = 0.f;
#pragma unroll
  for (int j = 0; j < 3; ++j) {
    v[j] = *(const float4*)&xr[j * 256 + lane * 4];
    s += v[j].x + v[j].y + v[j].z + v[j].w;
    ss += v[j].x * v[j].x + v[j].y * v[j].y + v[j].z * v[j].z + v[j].w * v[j].w;
  }
#pragma unroll
  for (int d = 1; d < 64; d <<= 1) {
    s += __shfl_xor(s, d);
    ss += __shfl_xor(ss, d);
  }
  float mu = s * (1.0f / DD);
  float rstd = rsqrtf(ss * (1.0f / DD) - mu * mu + 1e-5f);
  float* orow = out + (size_t)row * DD;
#pragma unroll
  for (int j = 0; j < 3; ++j) {
    float4 g = *(const float4*)&gamma[j * 256 + lane * 4];
    float4 be = *(const float4*)&beta[j * 256 + lane * 4];
    float4 r;
    r.x = (v[j].x - mu) * rstd * g.x + be.x;
    r.y = (v[j].y - mu) * rstd * g.y + be.y;
    r.z = (v[j].z - mu) * rstd * g.z + be.z;
    r.w = (v[j].w - mu) * rstd * g.w + be.w;
    *(float4*)&orow[j * 256 + lane * 4] = r;
  }
}

extern "C" void kernel_launch(void* const* d_in, const int* in_sizes, int n_in,
                              void* d_out, int out_size, void* d_ws, size_t ws_size,
                              hipStream_t stream) {
  (void)in_sizes; (void)n_in; (void)out_size; (void)ws_size;
  const float* ctx   = (const float*)d_in[0];
  const float* mask  = (const float*)d_in[1];
  const float* wqkv  = (const float*)d_in[2];
  const float* wproj = (const float*)d_in[3];
  const float* bproj = (const float*)d_in[4];
  const float* gamma = (const float*)d_in[5];
  const float* beta  = (const float*)d_in[6];
  float* out = (float*)d_out;

  char* p = (char*)d_ws;
  unsigned short* Xbf = (unsigned short*)p; p += (size_t)NEL * 2;
  unsigned short* Qw  = (unsigned short*)p; p += (size_t)NEL * 2;
  unsigned short* Kw  = (unsigned short*)p; p += (size_t)NEL * 2;
  unsigned short* Vtw = (unsigned short*)p; p += (size_t)NEL * 2;
  unsigned short* Ao  = (unsigned short*)p; p += (size_t)NEL * 2;
  unsigned short* WqkvT  = (unsigned short*)p; p += (size_t)DD * NQKV * 2;
  unsigned short* WprojT = (unsigned short*)p; p += (size_t)DD * DD * 2;
  float* xf = (float*)Qw;  // reuse Q+K region (attn done before proj writes)

  prep_k<<<PREP_PACK + PREP_TQKV + PREP_TPROJ, 256, 0, stream>>>(
      ctx, Xbf, wqkv, WqkvT, wproj, WprojT);
  gemm_qkv_k<<<dim3(BS / 128, NQKV / 128), 256, 0, stream>>>(WqkvT, Xbf, Qw, Kw, Vtw);
  attn_k<<<dim3(SS / 128, BB * HH), 256, 0, stream>>>(Qw, Kw, Vtw, mask, Ao);
  gemm_proj_k<<<dim3(BS / 128, DD / 128), 256, 0, stream>>>(WprojT, Ao, ctx, bproj, xf);
  ln_k<<<BS / 4, 256, 0, stream>>>(xf, gamma, beta, out);
}

// Round 10
// 251.330 us; speedup vs baseline: 1.0395x; 1.0395x over previous
//
#include <hip/hip_runtime.h>

// ---- constants for B=4, S=2048, D=768, H=12, HD=64 ----
#define BB 4
#define SS 2048
#define DD 768
#define HH 12
#define HDD 64
#define BS (BB*SS)            // 8192 rows
#define NQKV (3*DD)           // 2304
#define NEL (BS*DD)           // 6291456

typedef __attribute__((ext_vector_type(8))) __bf16 bf16x8;
typedef __attribute__((ext_vector_type(4))) float fx4;
typedef __attribute__((ext_vector_type(4))) int   ix4;

#define MFMA16(a,b,c) __builtin_amdgcn_mfma_f32_16x16x32_bf16((a),(b),(c),0,0,0)

// async global->LDS, 16B per lane, lane-linear dest (wave-uniform base + lane*16)
#define GLLDS(g, l) __builtin_amdgcn_global_load_lds( \
    (const __attribute__((address_space(1))) void*)(g), \
    (__attribute__((address_space(3))) void*)(l), 16, 0, 0)

__device__ __forceinline__ unsigned short f2bf(float f) {
  unsigned u = __builtin_bit_cast(unsigned, f);
  u = (u + 0x7FFFu + ((u >> 16) & 1u)) >> 16;
  return (unsigned short)u;
}
// pack two fp32 -> bf16 pair
__device__ __forceinline__ unsigned pkbf(float a, float b) {
  unsigned ua = __builtin_bit_cast(unsigned, a);
  unsigned ub = __builtin_bit_cast(unsigned, b);
  return ((ua + 0x8000u) >> 16) | ((ub + 0x8000u) & 0xFFFF0000u);
}
// hardware packed fp32->bf16 (RNE), 1 instr for 2 elems
__device__ __forceinline__ unsigned cvtpk(float a, float b) {
  unsigned r;
  asm("v_cvt_pk_bf16_f32 %0, %1, %2" : "=v"(r) : "v"(a), "v"(b));
  return r;
}
__device__ __forceinline__ float ex2(float x) { return __builtin_amdgcn_exp2f(x); }

// ---- fused prep: pack ctx->bf16 + transpose both weight matrices ----
#define PREP_PACK   6144
#define PREP_TQKV   1728   // 72 x 24 tiles
#define PREP_TPROJ  576    // 24 x 24 tiles
__global__ __launch_bounds__(256) void prep_k(const float* __restrict__ ctx,
                                              unsigned short* __restrict__ Xbf,
                                              const float* __restrict__ wqkv,
                                              unsigned short* __restrict__ WqkvT,
                                              const float* __restrict__ wproj,
                                              unsigned short* __restrict__ WprojT) {
  __shared__ unsigned short t[32][33];
  const int bid = blockIdx.x;
  const int tid = threadIdx.x;
  if (bid < PREP_PACK) {
    int i = bid * 256 + tid;
    float4 v = ((const float4*)ctx)[i];
    ((uint2*)Xbf)[i] = make_uint2(pkbf(v.x, v.y), pkbf(v.z, v.w));
    return;
  }
  const float* w; unsigned short* wT; int K, N, bx, by;
  if (bid < PREP_PACK + PREP_TQKV) {
    int tix = bid - PREP_PACK;
    w = wqkv; wT = WqkvT; K = DD; N = NQKV;
    bx = tix % 72; by = tix / 72;
  } else {
    int tix = bid - PREP_PACK - PREP_TQKV;
    w = wproj; wT = WprojT; K = DD; N = DD;
    bx = tix % 24; by = tix / 24;
  }
  int n0 = bx * 32, k0 = by * 32;
  int tx = tid & 31, ty = tid >> 5;
#pragma unroll
  for (int r = ty; r < 32; r += 8)
    t[tx][r] = f2bf(w[(size_t)(k0 + r) * N + n0 + tx]);
  __syncthreads();
#pragma unroll
  for (int r = ty; r < 32; r += 8)
    wT[(size_t)(n0 + r) * K + k0 + tx] = t[r][tx];
}

// XCD-aware block swizzle (requires nwg % 8 == 0; both GEMM grids satisfy)
__device__ __forceinline__ void xcd_swz(int gx, int* bx, int* by) {
  int nwg = gx * gridDim.y;
  int flat = blockIdx.y * gx + blockIdx.x;
  int cpx = nwg >> 3;
  int swz = (flat & 7) * cpx + (flat >> 3);
  *bx = swz % gx;
  *by = swz / gx;
}

// ==== QKV GEMM: C^T[feature][seq] = Wt(2304x768) x X(8192x768)^T ====
// 128x128 tile, BK=32, 3-buffer GLLDS ring with raw s_barrier + COUNTED vmcnt:
// iter t issues tile t+2; waits vmcnt(4) (tile t complete, t+1/t+2 in flight).
__global__ __launch_bounds__(256) void gemm_qkv_k(const unsigned short* __restrict__ Wt,
                                                  const unsigned short* __restrict__ X,
                                                  unsigned short* __restrict__ Qo,
                                                  unsigned short* __restrict__ Ko,
                                                  unsigned short* __restrict__ Vto) {
  __shared__ unsigned short As[3 * 128 * 32];   // 3 x 8KB ring
  __shared__ unsigned short Bs[3 * 128 * 32];
  const int tid = threadIdx.x;
  const int w = tid >> 6, lane = tid & 63, quad = lane >> 4, l16 = lane & 15;
  int bx, by; xcd_swz(gridDim.x, &bx, &by);
  const int m0 = by << 7;   // feature
  const int n0 = bx << 7;   // seq row
  const int wm = (w & 1) * 64, wn = (w >> 1) * 64;
  fx4 acc[4][4];
#pragma unroll
  for (int i = 0; i < 4; ++i)
#pragma unroll
    for (int c = 0; c < 4; ++c) acc[i][c] = (fx4){0.f, 0.f, 0.f, 0.f};

  const int c0 = tid, c1 = 256 + tid;
  const unsigned short* Ag0 = Wt + (size_t)(m0 + (c0 >> 2)) * DD + (c0 & 3) * 8;
  const unsigned short* Ag1 = Wt + (size_t)(m0 + (c1 >> 2)) * DD + (c1 & 3) * 8;
  const unsigned short* Bg0 = X + (size_t)(n0 + (c0 >> 2)) * DD + (c0 & 3) * 8;
  const unsigned short* Bg1 = X + (size_t)(n0 + (c1 >> 2)) * DD + (c1 & 3) * 8;
  const int wb = w * 1024;   // wave's lane-linear LDS byte base

  // prologue: tiles 0,1 -> bufs 0,1 (FIFO order: t0's 4 loads oldest)
  GLLDS(Ag0, (char*)As + wb);
  GLLDS(Ag1, (char*)As + 4096 + wb);
  GLLDS(Bg0, (char*)Bs + wb);
  GLLDS(Bg1, (char*)Bs + 4096 + wb);
  GLLDS(Ag0 + 32, (char*)As + 8192 + wb);
  GLLDS(Ag1 + 32, (char*)As + 8192 + 4096 + wb);
  GLLDS(Bg0 + 32, (char*)Bs + 8192 + wb);
  GLLDS(Bg1 + 32, (char*)Bs + 8192 + 4096 + wb);
  int cur = 0, wr = 2;

  for (int k0 = 0; k0 < DD; k0 += 32) {
    if (k0 + 32 < DD) {
      asm volatile("s_waitcnt vmcnt(4)" ::: "memory");   // oldest tile landed
    } else {
      asm volatile("s_waitcnt vmcnt(0)" ::: "memory");   // last tile: drain
    }
    __builtin_amdgcn_s_barrier();        // raw: no compiler waitcnt drain
    __builtin_amdgcn_sched_barrier(0);   // pin LDS reads below barrier
    if (k0 + 64 < DD) {                  // issue tile t+2 into buf last read at t-1
      GLLDS(Ag0 + k0 + 64, (char*)As + wr * 8192 + wb);
      GLLDS(Ag1 + k0 + 64, (char*)As + wr * 8192 + 4096 + wb);
      GLLDS(Bg0 + k0 + 64, (char*)Bs + wr * 8192 + wb);
      GLLDS(Bg1 + k0 + 64, (char*)Bs + wr * 8192 + 4096 + wb);
    }
    const unsigned short* Asc = As + cur * 4096;
    const unsigned short* Bsc = Bs + cur * 4096;
    bf16x8 af[4], bf[4];
#pragma unroll
    for (int i = 0; i < 4; ++i) af[i] = *(const bf16x8*)&Asc[(wm + i * 16 + l16) * 32 + quad * 8];
#pragma unroll
    for (int c = 0; c < 4; ++c) bf[c] = *(const bf16x8*)&Bsc[(wn + c * 16 + l16) * 32 + quad * 8];
#pragma unroll
    for (int i = 0; i < 4; ++i)
#pragma unroll
      for (int c = 0; c < 4; ++c) acc[i][c] = MFMA16(af[i], bf[c], acc[i][c]);
    cur = (cur == 2) ? 0 : cur + 1;
    wr  = (wr == 2) ? 0 : wr + 1;
  }

  const int which = m0 / DD;  // block-uniform: 0=Q 1=K 2=V (768 = 6*128, no straddle)
#pragma unroll
  for (int i = 0; i < 4; ++i) {
    int fb = m0 + wm + i * 16 + quad * 4;
    int d = fb - which * DD;
    int h = d >> 6, hd = d & 63;
#pragma unroll
    for (int c = 0; c < 4; ++c) {
      int srow = n0 + wn + c * 16 + l16;
      int b = srow >> 11, s = srow & (SS - 1);
      if (which == 0) {
        uint2 v = make_uint2(pkbf(acc[i][c][0], acc[i][c][1]), pkbf(acc[i][c][2], acc[i][c][3]));
        *(uint2*)&Qo[((size_t)(b * HH + h) * SS + s) * HDD + hd] = v;
      } else if (which == 1) {
        uint2 v = make_uint2(pkbf(acc[i][c][0], acc[i][c][1]), pkbf(acc[i][c][2], acc[i][c][3]));
        *(uint2*)&Ko[((size_t)(b * HH + h) * SS + s) * HDD + hd] = v;
      } else {
#pragma unroll
        for (int r = 0; r < 4; ++r)
          Vto[((size_t)(b * HH + h) * HDD + hd + r) * SS + s] = f2bf(acc[i][c][r]);
      }
    }
  }
}

// ==== proj GEMM: C^T[feat][seq] = WprojT(768x768) x Ao(8192x768)^T ====
// Same 3-buffer counted-vmcnt ring. Epilogue: + b_proj + residual(ctx), fp32 out.
__global__ __launch_bounds__(256) void gemm_proj_k(const unsigned short* __restrict__ Wt,
                                                   const unsigned short* __restrict__ X,
                                                   const float* __restrict__ ctx,
                                                   const float* __restrict__ bproj,
                                                   float* __restrict__ xf) {
  __shared__ unsigned short As[3 * 128 * 32];
  __shared__ unsigned short Bs[3 * 128 * 32];
  const int tid = threadIdx.x;
  const int w = tid >> 6, lane = tid & 63, quad = lane >> 4, l16 = lane & 15;
  int bx, by; xcd_swz(gridDim.x, &bx, &by);
  const int m0 = by << 7;
  const int n0 = bx << 7;
  const int wm = (w & 1) * 64, wn = (w >> 1) * 64;
  fx4 acc[4][4];
#pragma unroll
  for (int i = 0; i < 4; ++i)
#pragma unroll
    for (int c = 0; c < 4; ++c) acc[i][c] = (fx4){0.f, 0.f, 0.f, 0.f};

  const int c0 = tid, c1 = 256 + tid;
  const unsigned short* Ag0 = Wt + (size_t)(m0 + (c0 >> 2)) * DD + (c0 & 3) * 8;
  const unsigned short* Ag1 = Wt + (size_t)(m0 + (c1 >> 2)) * DD + (c1 & 3) * 8;
  const unsigned short* Bg0 = X + (size_t)(n0 + (c0 >> 2)) * DD + (c0 & 3) * 8;
  const unsigned short* Bg1 = X + (size_t)(n0 + (c1 >> 2)) * DD + (c1 & 3) * 8;
  const int wb = w * 1024;

  GLLDS(Ag0, (char*)As + wb);
  GLLDS(Ag1, (char*)As + 4096 + wb);
  GLLDS(Bg0, (char*)Bs + wb);
  GLLDS(Bg1, (char*)Bs + 4096 + wb);
  GLLDS(Ag0 + 32, (char*)As + 8192 + wb);
  GLLDS(Ag1 + 32, (char*)As + 8192 + 4096 + wb);
  GLLDS(Bg0 + 32, (char*)Bs + 8192 + wb);
  GLLDS(Bg1 + 32, (char*)Bs + 8192 + 4096 + wb);
  int cur = 0, wr = 2;

  for (int k0 = 0; k0 < DD; k0 += 32) {
    if (k0 + 32 < DD) {
      asm volatile("s_waitcnt vmcnt(4)" ::: "memory");
    } else {
      asm volatile("s_waitcnt vmcnt(0)" ::: "memory");
    }
    __builtin_amdgcn_s_barrier();
    __builtin_amdgcn_sched_barrier(0);
    if (k0 + 64 < DD) {
      GLLDS(Ag0 + k0 + 64, (char*)As + wr * 8192 + wb);
      GLLDS(Ag1 + k0 + 64, (char*)As + wr * 8192 + 4096 + wb);
      GLLDS(Bg0 + k0 + 64, (char*)Bs + wr * 8192 + wb);
      GLLDS(Bg1 + k0 + 64, (char*)Bs + wr * 8192 + 4096 + wb);
    }
    const unsigned short* Asc = As + cur * 4096;
    const unsigned short* Bsc = Bs + cur * 4096;
    bf16x8 af[4], bf[4];
#pragma unroll
    for (int i = 0; i < 4; ++i) af[i] = *(const bf16x8*)&Asc[(wm + i * 16 + l16) * 32 + quad * 8];
#pragma unroll
    for (int c = 0; c < 4; ++c) bf[c] = *(const bf16x8*)&Bsc[(wn + c * 16 + l16) * 32 + quad * 8];
#pragma unroll
    for (int i = 0; i < 4; ++i)
#pragma unroll
      for (int c = 0; c < 4; ++c) acc[i][c] = MFMA16(af[i], bf[c], acc[i][c]);
    cur = (cur == 2) ? 0 : cur + 1;
    wr  = (wr == 2) ? 0 : wr + 1;
  }

#pragma unroll
  for (int i = 0; i < 4; ++i) {
    int fb = m0 + wm + i * 16 + quad * 4;
    float4 bp = *(const float4*)&bproj[fb];
#pragma unroll
    for (int c = 0; c < 4; ++c) {
      int srow = n0 + wn + c * 16 + l16;
      float4 cx = *(const float4*)&ctx[(size_t)srow * DD + fb];
      float4 r;
      r.x = acc[i][c][0] + bp.x + cx.x;
      r.y = acc[i][c][1] + bp.y + cx.y;
      r.z = acc[i][c][2] + bp.z + cx.z;
      r.w = acc[i][c][3] + bp.w + cx.w;
      *(float4*)&xf[(size_t)srow * DD + fb] = r;
    }
  }
}

// ==== attention: S^T = K·Q^T; P stays in registers (k-permuted PV) ====
// block = 128 q-rows x one (b,h); 4 waves x 32 q-rows; 64-key tiles.
// VERIFIED structure (rounds 6/8: 83.5-85.8us): reg prefetch + ds_write phase,
// 2 barriers/tile. Two single-barrier variants (r7 ds_write-in-FIFO, r9 GLLDS
// vmcnt(0)) both regressed — do not touch this sync structure.
__global__ __launch_bounds__(256) void attn_k(const unsigned short* __restrict__ Q,
                                              const unsigned short* __restrict__ K,
                                              const unsigned short* __restrict__ Vt,
                                              const float* __restrict__ mask,
                                              unsigned short* __restrict__ O) {
  __shared__ unsigned short Ks[64 * 64];   // [key][dd], 16B chunks XOR-swizzled by row&7
  __shared__ unsigned short Vts[64 * 64];  // [hd][key], same swizzle
  __shared__ float kaS[SS];                // per-key softmax coeff a (8KB)
  __shared__ float kbS[SS];                // per-key softmax coeff b (8KB)
  const int tid = threadIdx.x;
  const int w = tid >> 6, lane = tid & 63;
  const int quad = lane >> 4, l16 = lane & 15;
  const int bh = blockIdx.y;
  const int b = bh / HH, h = bh - b * HH;
  const int q0 = blockIdx.x << 7;
  const unsigned short* Qb = Q + (size_t)bh * (SS * HDD);
  const unsigned short* Kb = K + (size_t)bh * (SS * HDD);
  const unsigned short* Vtb = Vt + (size_t)bh * (SS * HDD);
  const float* mb = mask + b * SS;

  // one-time: mask -> softmax coeffs, staged to LDS
  //   p = exp2(sc*ka + kb); ka = m*0.125*log2e; kb = (m-1)*1e10*log2e
#pragma unroll
  for (int i = 0; i < 2; ++i) {
    int idx = i * 256 + tid;                        // 512 float4 per table
    float4 mv = ((const float4*)mb)[idx];
    float4 a, c;
    a.x = mv.x * 0.18033688f; a.y = mv.y * 0.18033688f;
    a.z = mv.z * 0.18033688f; a.w = mv.w * 0.18033688f;
    c.x = __builtin_fmaf(mv.x, 1.44269504e10f, -1.44269504e10f);
    c.y = __builtin_fmaf(mv.y, 1.44269504e10f, -1.44269504e10f);
    c.z = __builtin_fmaf(mv.z, 1.44269504e10f, -1.44269504e10f);
    c.w = __builtin_fmaf(mv.w, 1.44269504e10f, -1.44269504e10f);
    ((float4*)kaS)[idx] = a;
    ((float4*)kbS)[idx] = c;
  }

  // Q fragments (B-operand: n=q=l16, k=dd natural)
  bf16x8 qf[2][2];
#pragma unroll
  for (int qi = 0; qi < 2; ++qi)
#pragma unroll
    for (int f = 0; f < 2; ++f)
      qf[qi][f] = *(const bf16x8*)&Qb[(size_t)(q0 + w * 32 + qi * 16 + l16) * HDD + f * 32 + quad * 8];

  fx4 o[2][4];
#pragma unroll
  for (int qi = 0; qi < 2; ++qi)
#pragma unroll
    for (int ht = 0; ht < 4; ++ht) o[qi][ht] = (fx4){0.f, 0.f, 0.f, 0.f};
  fx4 sacc[2];
  sacc[0] = (fx4){0.f, 0.f, 0.f, 0.f};
  sacc[1] = (fx4){0.f, 0.f, 0.f, 0.f};

  // ones fragment for row-sum MFMA (A all 1.0bf16 -> D[m][q] = sum_k P[k][q])
  const ix4 one4 = (ix4){0x3F803F80, 0x3F803F80, 0x3F803F80, 0x3F803F80};
  const bf16x8 onesf = __builtin_bit_cast(bf16x8, one4);

  // staging: 512 chunks of 16B per matrix; 2 per thread; XOR-swizzled placement
  const int cA = tid, cB = 256 + tid;
  const int rA = cA >> 3, pA = (cA & 7) ^ (rA & 7);
  const int rB = cB >> 3, pB = (cB & 7) ^ (rB & 7);

  ix4 rk0 = *(const ix4*)&Kb[(size_t)rA * HDD + pA * 8];
  ix4 rk1 = *(const ix4*)&Kb[(size_t)rB * HDD + pB * 8];
  ix4 rv0 = *(const ix4*)&Vtb[(size_t)rA * SS + pA * 8];
  ix4 rv1 = *(const ix4*)&Vtb[(size_t)rB * SS + pB * 8];

  for (int k0 = 0; k0 < SS; k0 += 64) {
    __syncthreads();
    *(ix4*)((char*)Ks + cA * 16) = rk0;
    *(ix4*)((char*)Ks + cB * 16) = rk1;
    *(ix4*)((char*)Vts + cA * 16) = rv0;
    *(ix4*)((char*)Vts + cB * 16) = rv1;
    __syncthreads();
    if (k0 + 64 < SS) {
      int kn = k0 + 64;
      rk0 = *(const ix4*)&Kb[(size_t)(kn + rA) * HDD + pA * 8];
      rk1 = *(const ix4*)&Kb[(size_t)(kn + rB) * HDD + pB * 8];
      rv0 = *(const ix4*)&Vtb[(size_t)rA * SS + kn + pA * 8];
      rv1 = *(const ix4*)&Vtb[(size_t)rB * SS + kn + pB * 8];
    }

    // mask coefficients from LDS (lgkmcnt only)
    float4 mqa[4], mqb[4];
#pragma unroll
    for (int kt = 0; kt < 4; ++kt) {
      mqa[kt] = *(const float4*)&kaS[k0 + kt * 16 + quad * 4];
      mqb[kt] = *(const float4*)&kbS[k0 + kt * 16 + quad * 4];
    }

    // K fragments (A-operand: m=key=l16, k=dd natural)
    bf16x8 kf[4][2];
#pragma unroll
    for (int kt = 0; kt < 4; ++kt) {
      int row = kt * 16 + l16;
      int rx = row & 7;
#pragma unroll
      for (int f = 0; f < 2; ++f)
        kf[kt][f] = *(const bf16x8*)&Ks[row * 64 + ((f * 4 + quad) ^ rx) * 8];
    }
    // V fragments (A-operand: m=hd=l16, k-permuted: key=f*32+(j>>2)*16+quad*4+(j&3))
    bf16x8 vf[4][2];
#pragma unroll
    for (int ht = 0; ht < 4; ++ht) {
      int row = ht * 16 + l16;
      int rx = row & 7;
#pragma unroll
      for (int f = 0; f < 2; ++f) {
        int dc0 = (f * 4 + (quad >> 1)) ^ rx;
        int dc1 = (f * 4 + 2 + (quad >> 1)) ^ rx;
        uint2 lo = *(const uint2*)((const char*)Vts + row * 128 + dc0 * 16 + (quad & 1) * 8);
        uint2 hi = *(const uint2*)((const char*)Vts + row * 128 + dc1 * 16 + (quad & 1) * 8);
        ix4 vv = (ix4){(int)lo.x, (int)lo.y, (int)hi.x, (int)hi.y};
        vf[ht][f] = __builtin_bit_cast(bf16x8, vv);
      }
    }

#pragma unroll
    for (int qi = 0; qi < 2; ++qi) {
      unsigned pw[8];
#pragma unroll
      for (int kt = 0; kt < 4; ++kt) {
        fx4 s = (fx4){0.f, 0.f, 0.f, 0.f};
        s = MFMA16(kf[kt][0], qf[qi][0], s);
        s = MFMA16(kf[kt][1], qf[qi][1], s);
        const float* ma = (const float*)&mqa[kt];
        const float* mc = (const float*)&mqb[kt];
        float p0 = ex2(__builtin_fmaf(s[0], ma[0], mc[0]));
        float p1 = ex2(__builtin_fmaf(s[1], ma[1], mc[1]));
        float p2 = ex2(__builtin_fmaf(s[2], ma[2], mc[2]));
        float p3 = ex2(__builtin_fmaf(s[3], ma[3], mc[3]));
        pw[kt * 2]     = cvtpk(p0, p1);
        pw[kt * 2 + 1] = cvtpk(p2, p3);
      }
      ix4 pi0 = (ix4){(int)pw[0], (int)pw[1], (int)pw[2], (int)pw[3]};
      ix4 pi1 = (ix4){(int)pw[4], (int)pw[5], (int)pw[6], (int)pw[7]};
      bf16x8 pf0 = __builtin_bit_cast(bf16x8, pi0);
      bf16x8 pf1 = __builtin_bit_cast(bf16x8, pi1);
      // row-sum on the MFMA pipe
      sacc[qi] = MFMA16(onesf, pf0, sacc[qi]);
      sacc[qi] = MFMA16(onesf, pf1, sacc[qi]);
#pragma unroll
      for (int ht = 0; ht < 4; ++ht) {
        o[qi][ht] = MFMA16(vf[ht][0], pf0, o[qi][ht]);
        o[qi][ht] = MFMA16(vf[ht][1], pf1, o[qi][ht]);
      }
    }
  }

#pragma unroll
  for (int qi = 0; qi < 2; ++qi) {
    // sacc rows are all identical (ones operand): lane's col l16 sum is in any reg
    float inv = 1.f / fmaxf(sacc[qi][0], 1e-30f);
    int sq = q0 + w * 32 + qi * 16 + l16;
    unsigned short* orow = O + ((size_t)(b * SS + sq)) * DD + h * HDD;
#pragma unroll
    for (int ht = 0; ht < 4; ++ht) {
      uint2 v = make_uint2(pkbf(o[qi][ht][0] * inv, o[qi][ht][1] * inv),
                           pkbf(o[qi][ht][2] * inv, o[qi][ht][3] * inv));
      *(uint2*)&orow[ht * 16 + quad * 4] = v;
    }
  }
}

// ---- LayerNorm over D=768: one WAVE per row, 4 rows/block, no barriers ----
__global__ __launch_bounds__(256) void ln_k(const float* __restrict__ x,
                                            const float* __restrict__ gamma,
                                            const float* __restrict__ beta,
                                            float* __restrict__ out) {
  const int wv = threadIdx.x >> 6, lane = threadIdx.x & 63;
  const int row = blockIdx.x * 4 + wv;
  const float* xr = x + (size_t)row * DD;
  float4 v[3];
  float s = 0.f, ss = 0.f;
#pragma unroll
  for (int j = 0; j < 3; ++j) {
    v[j] = *(const float4*)&xr[j * 256 + lane * 4];
    s += v[j].x + v[j].y + v[j].z + v[j].w;
    ss += v[j].x * v[j].x + v[j].y * v[j].y + v[j].z * v[j].z + v[j].w * v[j].w;
  }
#pragma unroll
  for (int d = 1; d < 64; d <<= 1) {
    s += __shfl_xor(s, d);
    ss += __shfl_xor(ss, d);
  }
  float mu = s * (1.0f / DD);
  float rstd = rsqrtf(ss * (1.0f / DD) - mu * mu + 1e-5f);
  float* orow = out + (size_t)row * DD;
#pragma unroll
  for (int j = 0; j < 3; ++j) {
    float4 g = *(const float4*)&gamma[j * 256 + lane * 4];
    float4 be = *(const float4*)&beta[j * 256 + lane * 4];
    float4 r;
    r.x = (v[j].x - mu) * rstd * g.x + be.x;
    r.y = (v[j].y - mu) * rstd * g.y + be.y;
    r.z = (v[j].z - mu) * rstd * g.z + be.z;
    r.w = (v[j].w - mu) * rstd * g.w + be.w;
    *(float4*)&orow[j * 256 + lane * 4] = r;
  }
}

extern "C" void kernel_launch(void* const* d_in, const int* in_sizes, int n_in,
                              void* d_out, int out_size, void* d_ws, size_t ws_size,
                              hipStream_t stream) {
  (void)in_sizes; (void)n_in; (void)out_size; (void)ws_size;
  const float* ctx   = (const float*)d_in[0];
  const float* mask  = (const float*)d_in[1];
  const float* wqkv  = (const float*)d_in[2];
  const float* wproj = (const float*)d_in[3];
  const float* bproj = (const float*)d_in[4];
  const float* gamma = (const float*)d_in[5];
  const float* beta  = (const float*)d_in[6];
  float* out = (float*)d_out;

  char* p = (char*)d_ws;
  unsigned short* Xbf = (unsigned short*)p; p += (size_t)NEL * 2;
  unsigned short* Qw  = (unsigned short*)p; p += (size_t)NEL * 2;
  unsigned short* Kw  = (unsigned short*)p; p += (size_t)NEL * 2;
  unsigned short* Vtw = (unsigned short*)p; p += (size_t)NEL * 2;
  unsigned short* Ao  = (unsigned short*)p; p += (size_t)NEL * 2;
  unsigned short* WqkvT  = (unsigned short*)p; p += (size_t)DD * NQKV * 2;
  unsigned short* WprojT = (unsigned short*)p; p += (size_t)DD * DD * 2;
  float* xf = (float*)Qw;  // reuse Q+K region (attn done before proj writes)

  prep_k<<<PREP_PACK + PREP_TQKV + PREP_TPROJ, 256, 0, stream>>>(
      ctx, Xbf, wqkv, WqkvT, wproj, WprojT);
  gemm_qkv_k<<<dim3(BS / 128, NQKV / 128), 256, 0, stream>>>(WqkvT, Xbf, Qw, Kw, Vtw);
  attn_k<<<dim3(SS / 128, BB * HH), 256, 0, stream>>>(Qw, Kw, Vtw, mask, Ao);
  gemm_proj_k<<<dim3(BS / 128, DD / 128), 256, 0, stream>>>(WprojT, Ao, ctx, bproj, xf);
  ln_k<<<BS / 4, 256, 0, stream>>>(xf, gamma, beta, out);
}

// Round 11
// 248.690 us; speedup vs baseline: 1.0506x; 1.0106x over previous
//
#include <hip/hip_runtime.h>

// ---- constants for B=4, S=2048, D=768, H=12, HD=64 ----
#define BB 4
#define SS 2048
#define DD 768
#define HH 12
#define HDD 64
#define BS (BB*SS)            // 8192 rows
#define NQKV (3*DD)           // 2304
#define NEL (BS*DD)           // 6291456

typedef __attribute__((ext_vector_type(8))) __bf16 bf16x8;
typedef __attribute__((ext_vector_type(4))) float fx4;
typedef __attribute__((ext_vector_type(4))) int   ix4;

#define MFMA16(a,b,c) __builtin_amdgcn_mfma_f32_16x16x32_bf16((a),(b),(c),0,0,0)

// async global->LDS, 16B per lane, lane-linear dest (wave-uniform base + lane*16)
#define GLLDS(g, l) __builtin_amdgcn_global_load_lds( \
    (const __attribute__((address_space(1))) void*)(g), \
    (__attribute__((address_space(3))) void*)(l), 16, 0, 0)

__device__ __forceinline__ unsigned short f2bf(float f) {
  unsigned u = __builtin_bit_cast(unsigned, f);
  u = (u + 0x7FFFu + ((u >> 16) & 1u)) >> 16;
  return (unsigned short)u;
}
// pack two fp32 -> bf16 pair
__device__ __forceinline__ unsigned pkbf(float a, float b) {
  unsigned ua = __builtin_bit_cast(unsigned, a);
  unsigned ub = __builtin_bit_cast(unsigned, b);
  return ((ua + 0x8000u) >> 16) | ((ub + 0x8000u) & 0xFFFF0000u);
}
// hardware packed fp32->bf16 (RNE), 1 instr for 2 elems
__device__ __forceinline__ unsigned cvtpk(float a, float b) {
  unsigned r;
  asm("v_cvt_pk_bf16_f32 %0, %1, %2" : "=v"(r) : "v"(a), "v"(b));
  return r;
}
__device__ __forceinline__ float ex2(float x) { return __builtin_amdgcn_exp2f(x); }

// ---- fused prep: pack ctx->bf16 + transpose both weight matrices ----
#define PREP_PACK   6144
#define PREP_TQKV   1728   // 72 x 24 tiles
#define PREP_TPROJ  576    // 24 x 24 tiles
__global__ __launch_bounds__(256) void prep_k(const float* __restrict__ ctx,
                                              unsigned short* __restrict__ Xbf,
                                              const float* __restrict__ wqkv,
                                              unsigned short* __restrict__ WqkvT,
                                              const float* __restrict__ wproj,
                                              unsigned short* __restrict__ WprojT) {
  __shared__ unsigned short t[32][33];
  const int bid = blockIdx.x;
  const int tid = threadIdx.x;
  if (bid < PREP_PACK) {
    int i = bid * 256 + tid;
    float4 v = ((const float4*)ctx)[i];
    ((uint2*)Xbf)[i] = make_uint2(pkbf(v.x, v.y), pkbf(v.z, v.w));
    return;
  }
  const float* w; unsigned short* wT; int K, N, bx, by;
  if (bid < PREP_PACK + PREP_TQKV) {
    int tix = bid - PREP_PACK;
    w = wqkv; wT = WqkvT; K = DD; N = NQKV;
    bx = tix % 72; by = tix / 72;
  } else {
    int tix = bid - PREP_PACK - PREP_TQKV;
    w = wproj; wT = WprojT; K = DD; N = DD;
    bx = tix % 24; by = tix / 24;
  }
  int n0 = bx * 32, k0 = by * 32;
  int tx = tid & 31, ty = tid >> 5;
#pragma unroll
  for (int r = ty; r < 32; r += 8)
    t[tx][r] = f2bf(w[(size_t)(k0 + r) * N + n0 + tx]);
  __syncthreads();
#pragma unroll
  for (int r = ty; r < 32; r += 8)
    wT[(size_t)(n0 + r) * K + k0 + tx] = t[r][tx];
}

// XCD-aware block swizzle (requires nwg % 8 == 0; both GEMM grids satisfy)
__device__ __forceinline__ void xcd_swz(int gx, int* bx, int* by) {
  int nwg = gx * gridDim.y;
  int flat = blockIdx.y * gx + blockIdx.x;
  int cpx = nwg >> 3;
  int swz = (flat & 7) * cpx + (flat >> 3);
  *bx = swz % gx;
  *by = swz / gx;
}

// ==== QKV GEMM: C^T[feature][seq] = Wt(2304x768) x X(8192x768)^T ====
// 128x128 tile, BK=32, 3-buffer GLLDS ring (raw s_barrier + counted vmcnt).
// NEW epilogue: LDS-transpose round-trip -> fully coalesced 128B stores for
// Q, K (per-[s][hd] rows) and V (per-[hd][s] rows). Replaces the scattered
// uint2 (16-segment) and scalar-V (64-segment) stores.
__global__ __launch_bounds__(256) void gemm_qkv_k(const unsigned short* __restrict__ Wt,
                                                  const unsigned short* __restrict__ X,
                                                  unsigned short* __restrict__ Qo,
                                                  unsigned short* __restrict__ Ko,
                                                  unsigned short* __restrict__ Vto) {
  __shared__ __align__(16) char smem[49152];
  unsigned short* As = (unsigned short*)smem;            // 3 x 8KB ring
  unsigned short* Bs = (unsigned short*)(smem + 24576);  // 3 x 8KB ring
  const int tid = threadIdx.x;
  const int w = tid >> 6, lane = tid & 63, quad = lane >> 4, l16 = lane & 15;
  int bx, by; xcd_swz(gridDim.x, &bx, &by);
  const int m0 = by << 7;   // feature
  const int n0 = bx << 7;   // seq row
  const int wm = (w & 1) * 64, wn = (w >> 1) * 64;
  fx4 acc[4][4];
#pragma unroll
  for (int i = 0; i < 4; ++i)
#pragma unroll
    for (int c = 0; c < 4; ++c) acc[i][c] = (fx4){0.f, 0.f, 0.f, 0.f};

  const int c0 = tid, c1 = 256 + tid;
  const unsigned short* Ag0 = Wt + (size_t)(m0 + (c0 >> 2)) * DD + (c0 & 3) * 8;
  const unsigned short* Ag1 = Wt + (size_t)(m0 + (c1 >> 2)) * DD + (c1 & 3) * 8;
  const unsigned short* Bg0 = X + (size_t)(n0 + (c0 >> 2)) * DD + (c0 & 3) * 8;
  const unsigned short* Bg1 = X + (size_t)(n0 + (c1 >> 2)) * DD + (c1 & 3) * 8;
  const int wb = w * 1024;   // wave's lane-linear LDS byte base

  // prologue: tiles 0,1 -> bufs 0,1 (FIFO order: t0's 4 loads oldest)
  GLLDS(Ag0, (char*)As + wb);
  GLLDS(Ag1, (char*)As + 4096 + wb);
  GLLDS(Bg0, (char*)Bs + wb);
  GLLDS(Bg1, (char*)Bs + 4096 + wb);
  GLLDS(Ag0 + 32, (char*)As + 8192 + wb);
  GLLDS(Ag1 + 32, (char*)As + 8192 + 4096 + wb);
  GLLDS(Bg0 + 32, (char*)Bs + 8192 + wb);
  GLLDS(Bg1 + 32, (char*)Bs + 8192 + 4096 + wb);
  int cur = 0, wr = 2;

  for (int k0 = 0; k0 < DD; k0 += 32) {
    if (k0 + 32 < DD) {
      asm volatile("s_waitcnt vmcnt(4)" ::: "memory");   // oldest tile landed
    } else {
      asm volatile("s_waitcnt vmcnt(0)" ::: "memory");   // last tile: drain
    }
    __builtin_amdgcn_s_barrier();        // raw: no compiler waitcnt drain
    __builtin_amdgcn_sched_barrier(0);   // pin LDS reads below barrier
    if (k0 + 64 < DD) {                  // issue tile t+2 into buf last read at t-1
      GLLDS(Ag0 + k0 + 64, (char*)As + wr * 8192 + wb);
      GLLDS(Ag1 + k0 + 64, (char*)As + wr * 8192 + 4096 + wb);
      GLLDS(Bg0 + k0 + 64, (char*)Bs + wr * 8192 + wb);
      GLLDS(Bg1 + k0 + 64, (char*)Bs + wr * 8192 + 4096 + wb);
    }
    const unsigned short* Asc = As + cur * 4096;
    const unsigned short* Bsc = Bs + cur * 4096;
    bf16x8 af[4], bf[4];
#pragma unroll
    for (int i = 0; i < 4; ++i) af[i] = *(const bf16x8*)&Asc[(wm + i * 16 + l16) * 32 + quad * 8];
#pragma unroll
    for (int c = 0; c < 4; ++c) bf[c] = *(const bf16x8*)&Bsc[(wn + c * 16 + l16) * 32 + quad * 8];
#pragma unroll
    for (int i = 0; i < 4; ++i)
#pragma unroll
      for (int c = 0; c < 4; ++c) acc[i][c] = MFMA16(af[i], bf[c], acc[i][c]);
    cur = (cur == 2) ? 0 : cur + 1;
    wr  = (wr == 2) ? 0 : wr + 1;
  }

  // ---- epilogue: transpose through LDS scratch (ring is dead now) ----
  // scratch rows padded to 136 elems (272B, 16B-aligned rows)
  unsigned short* t16 = (unsigned short*)smem;   // 128 x 136 x 2B = 34KB <= 48KB
  const int which = m0 / DD;  // block-uniform: 0=Q 1=K 2=V (no 128-tile straddle)
  __syncthreads();            // all waves done with ring reads; vmcnt already 0
#pragma unroll
  for (int i = 0; i < 4; ++i) {
    int fl = wm + i * 16 + quad * 4;
#pragma unroll
    for (int c = 0; c < 4; ++c) {
      int sl = wn + c * 16 + l16;
#pragma unroll
      for (int r = 0; r < 4; ++r) {
        unsigned short v = f2bf(acc[i][c][r]);
        // V wants [feature][s] rows; Q/K want [s][feature] rows
        int a = (which == 2) ? (fl + r) * 136 + sl : sl * 136 + (fl + r);
        t16[a] = v;
      }
    }
  }
  __syncthreads();
  const int row2 = tid >> 1, half = tid & 1;      // 128 rows x 2 halves
  const unsigned short* src = t16 + row2 * 136 + half * 64;   // 128B, 16B-aligned
  if (which == 2) {
    int d = m0 - 2 * DD + row2;                   // local feature -> (h, hd)
    int h = d >> 6, hd = d & 63;
    int bq = n0 >> 11, sb = n0 & (SS - 1);
    unsigned short* dst = Vto + ((size_t)(bq * HH + h) * HDD + hd) * SS + sb + half * 64;
#pragma unroll
    for (int j = 0; j < 4; ++j)
      *(ix4*)(dst + j * 8) = *(const ix4*)(src + j * 8);
  } else {
    int srow = n0 + row2;
    int bq = srow >> 11, s = srow & (SS - 1);
    int h = ((m0 - which * DD) >> 6) + half;      // tile spans 2 heads
    unsigned short* base = (which == 0) ? Qo : Ko;
    unsigned short* dst = base + ((size_t)(bq * HH + h) * SS + s) * HDD;
#pragma unroll
    for (int j = 0; j < 4; ++j)
      *(ix4*)(dst + j * 8) = *(const ix4*)(src + j * 8);
  }
}

// ==== proj GEMM: C^T[feat][seq] = WprojT(768x768) x Ao(8192x768)^T ====
// Same 3-buffer counted-vmcnt ring. Epilogue: + b_proj + residual(ctx), fp32 out.
__global__ __launch_bounds__(256) void gemm_proj_k(const unsigned short* __restrict__ Wt,
                                                   const unsigned short* __restrict__ X,
                                                   const float* __restrict__ ctx,
                                                   const float* __restrict__ bproj,
                                                   float* __restrict__ xf) {
  __shared__ unsigned short As[3 * 128 * 32];
  __shared__ unsigned short Bs[3 * 128 * 32];
  const int tid = threadIdx.x;
  const int w = tid >> 6, lane = tid & 63, quad = lane >> 4, l16 = lane & 15;
  int bx, by; xcd_swz(gridDim.x, &bx, &by);
  const int m0 = by << 7;
  const int n0 = bx << 7;
  const int wm = (w & 1) * 64, wn = (w >> 1) * 64;
  fx4 acc[4][4];
#pragma unroll
  for (int i = 0; i < 4; ++i)
#pragma unroll
    for (int c = 0; c < 4; ++c) acc[i][c] = (fx4){0.f, 0.f, 0.f, 0.f};

  const int c0 = tid, c1 = 256 + tid;
  const unsigned short* Ag0 = Wt + (size_t)(m0 + (c0 >> 2)) * DD + (c0 & 3) * 8;
  const unsigned short* Ag1 = Wt + (size_t)(m0 + (c1 >> 2)) * DD + (c1 & 3) * 8;
  const unsigned short* Bg0 = X + (size_t)(n0 + (c0 >> 2)) * DD + (c0 & 3) * 8;
  const unsigned short* Bg1 = X + (size_t)(n0 + (c1 >> 2)) * DD + (c1 & 3) * 8;
  const int wb = w * 1024;

  GLLDS(Ag0, (char*)As + wb);
  GLLDS(Ag1, (char*)As + 4096 + wb);
  GLLDS(Bg0, (char*)Bs + wb);
  GLLDS(Bg1, (char*)Bs + 4096 + wb);
  GLLDS(Ag0 + 32, (char*)As + 8192 + wb);
  GLLDS(Ag1 + 32, (char*)As + 8192 + 4096 + wb);
  GLLDS(Bg0 + 32, (char*)Bs + 8192 + wb);
  GLLDS(Bg1 + 32, (char*)Bs + 8192 + 4096 + wb);
  int cur = 0, wr = 2;

  for (int k0 = 0; k0 < DD; k0 += 32) {
    if (k0 + 32 < DD) {
      asm volatile("s_waitcnt vmcnt(4)" ::: "memory");
    } else {
      asm volatile("s_waitcnt vmcnt(0)" ::: "memory");
    }
    __builtin_amdgcn_s_barrier();
    __builtin_amdgcn_sched_barrier(0);
    if (k0 + 64 < DD) {
      GLLDS(Ag0 + k0 + 64, (char*)As + wr * 8192 + wb);
      GLLDS(Ag1 + k0 + 64, (char*)As + wr * 8192 + 4096 + wb);
      GLLDS(Bg0 + k0 + 64, (char*)Bs + wr * 8192 + wb);
      GLLDS(Bg1 + k0 + 64, (char*)Bs + wr * 8192 + 4096 + wb);
    }
    const unsigned short* Asc = As + cur * 4096;
    const unsigned short* Bsc = Bs + cur * 4096;
    bf16x8 af[4], bf[4];
#pragma unroll
    for (int i = 0; i < 4; ++i) af[i] = *(const bf16x8*)&Asc[(wm + i * 16 + l16) * 32 + quad * 8];
#pragma unroll
    for (int c = 0; c < 4; ++c) bf[c] = *(const bf16x8*)&Bsc[(wn + c * 16 + l16) * 32 + quad * 8];
#pragma unroll
    for (int i = 0; i < 4; ++i)
#pragma unroll
      for (int c = 0; c < 4; ++c) acc[i][c] = MFMA16(af[i], bf[c], acc[i][c]);
    cur = (cur == 2) ? 0 : cur + 1;
    wr  = (wr == 2) ? 0 : wr + 1;
  }

#pragma unroll
  for (int i = 0; i < 4; ++i) {
    int fb = m0 + wm + i * 16 + quad * 4;
    float4 bp = *(const float4*)&bproj[fb];
#pragma unroll
    for (int c = 0; c < 4; ++c) {
      int srow = n0 + wn + c * 16 + l16;
      float4 cx = *(const float4*)&ctx[(size_t)srow * DD + fb];
      float4 r;
      r.x = acc[i][c][0] + bp.x + cx.x;
      r.y = acc[i][c][1] + bp.y + cx.y;
      r.z = acc[i][c][2] + bp.z + cx.z;
      r.w = acc[i][c][3] + bp.w + cx.w;
      *(float4*)&xf[(size_t)srow * DD + fb] = r;
    }
  }
}

// ==== attention: S^T = K·Q^T; P stays in registers (k-permuted PV) ====
// block = 128 q-rows x one (b,h); 4 waves x 32 q-rows; 64-key tiles.
// VERIFIED structure (rounds 6/8/10: 83.5-85.8us): reg prefetch + ds_write
// phase, 2 barriers/tile. Single-barrier variants (r7, r9) both regressed —
// do not touch this sync structure.
__global__ __launch_bounds__(256) void attn_k(const unsigned short* __restrict__ Q,
                                              const unsigned short* __restrict__ K,
                                              const unsigned short* __restrict__ Vt,
                                              const float* __restrict__ mask,
                                              unsigned short* __restrict__ O) {
  __shared__ unsigned short Ks[64 * 64];   // [key][dd], 16B chunks XOR-swizzled by row&7
  __shared__ unsigned short Vts[64 * 64];  // [hd][key], same swizzle
  __shared__ float kaS[SS];                // per-key softmax coeff a (8KB)
  __shared__ float kbS[SS];                // per-key softmax coeff b (8KB)
  const int tid = threadIdx.x;
  const int w = tid >> 6, lane = tid & 63;
  const int quad = lane >> 4, l16 = lane & 15;
  const int bh = blockIdx.y;
  const int b = bh / HH, h = bh - b * HH;
  const int q0 = blockIdx.x << 7;
  const unsigned short* Qb = Q + (size_t)bh * (SS * HDD);
  const unsigned short* Kb = K + (size_t)bh * (SS * HDD);
  const unsigned short* Vtb = Vt + (size_t)bh * (SS * HDD);
  const float* mb = mask + b * SS;

  // one-time: mask -> softmax coeffs, staged to LDS
  //   p = exp2(sc*ka + kb); ka = m*0.125*log2e; kb = (m-1)*1e10*log2e
#pragma unroll
  for (int i = 0; i < 2; ++i) {
    int idx = i * 256 + tid;                        // 512 float4 per table
    float4 mv = ((const float4*)mb)[idx];
    float4 a, c;
    a.x = mv.x * 0.18033688f; a.y = mv.y * 0.18033688f;
    a.z = mv.z * 0.18033688f; a.w = mv.w * 0.18033688f;
    c.x = __builtin_fmaf(mv.x, 1.44269504e10f, -1.44269504e10f);
    c.y = __builtin_fmaf(mv.y, 1.44269504e10f, -1.44269504e10f);
    c.z = __builtin_fmaf(mv.z, 1.44269504e10f, -1.44269504e10f);
    c.w = __builtin_fmaf(mv.w, 1.44269504e10f, -1.44269504e10f);
    ((float4*)kaS)[idx] = a;
    ((float4*)kbS)[idx] = c;
  }

  // Q fragments (B-operand: n=q=l16, k=dd natural)
  bf16x8 qf[2][2];
#pragma unroll
  for (int qi = 0; qi < 2; ++qi)
#pragma unroll
    for (int f = 0; f < 2; ++f)
      qf[qi][f] = *(const bf16x8*)&Qb[(size_t)(q0 + w * 32 + qi * 16 + l16) * HDD + f * 32 + quad * 8];

  fx4 o[2][4];
#pragma unroll
  for (int qi = 0; qi < 2; ++qi)
#pragma unroll
    for (int ht = 0; ht < 4; ++ht) o[qi][ht] = (fx4){0.f, 0.f, 0.f, 0.f};
  fx4 sacc[2];
  sacc[0] = (fx4){0.f, 0.f, 0.f, 0.f};
  sacc[1] = (fx4){0.f, 0.f, 0.f, 0.f};

  // ones fragment for row-sum MFMA (A all 1.0bf16 -> D[m][q] = sum_k P[k][q])
  const ix4 one4 = (ix4){0x3F803F80, 0x3F803F80, 0x3F803F80, 0x3F803F80};
  const bf16x8 onesf = __builtin_bit_cast(bf16x8, one4);

  // staging: 512 chunks of 16B per matrix; 2 per thread; XOR-swizzled placement
  const int cA = tid, cB = 256 + tid;
  const int rA = cA >> 3, pA = (cA & 7) ^ (rA & 7);
  const int rB = cB >> 3, pB = (cB & 7) ^ (rB & 7);

  ix4 rk0 = *(const ix4*)&Kb[(size_t)rA * HDD + pA * 8];
  ix4 rk1 = *(const ix4*)&Kb[(size_t)rB * HDD + pB * 8];
  ix4 rv0 = *(const ix4*)&Vtb[(size_t)rA * SS + pA * 8];
  ix4 rv1 = *(const ix4*)&Vtb[(size_t)rB * SS + pB * 8];

  for (int k0 = 0; k0 < SS; k0 += 64) {
    __syncthreads();
    *(ix4*)((char*)Ks + cA * 16) = rk0;
    *(ix4*)((char*)Ks + cB * 16) = rk1;
    *(ix4*)((char*)Vts + cA * 16) = rv0;
    *(ix4*)((char*)Vts + cB * 16) = rv1;
    __syncthreads();
    if (k0 + 64 < SS) {
      int kn = k0 + 64;
      rk0 = *(const ix4*)&Kb[(size_t)(kn + rA) * HDD + pA * 8];
      rk1 = *(const ix4*)&Kb[(size_t)(kn + rB) * HDD + pB * 8];
      rv0 = *(const ix4*)&Vtb[(size_t)rA * SS + kn + pA * 8];
      rv1 = *(const ix4*)&Vtb[(size_t)rB * SS + kn + pB * 8];
    }

    // mask coefficients from LDS (lgkmcnt only)
    float4 mqa[4], mqb[4];
#pragma unroll
    for (int kt = 0; kt < 4; ++kt) {
      mqa[kt] = *(const float4*)&kaS[k0 + kt * 16 + quad * 4];
      mqb[kt] = *(const float4*)&kbS[k0 + kt * 16 + quad * 4];
    }

    // K fragments (A-operand: m=key=l16, k=dd natural)
    bf16x8 kf[4][2];
#pragma unroll
    for (int kt = 0; kt < 4; ++kt) {
      int row = kt * 16 + l16;
      int rx = row & 7;
#pragma unroll
      for (int f = 0; f < 2; ++f)
        kf[kt][f] = *(const bf16x8*)&Ks[row * 64 + ((f * 4 + quad) ^ rx) * 8];
    }
    // V fragments (A-operand: m=hd=l16, k-permuted: key=f*32+(j>>2)*16+quad*4+(j&3))
    bf16x8 vf[4][2];
#pragma unroll
    for (int ht = 0; ht < 4; ++ht) {
      int row = ht * 16 + l16;
      int rx = row & 7;
#pragma unroll
      for (int f = 0; f < 2; ++f) {
        int dc0 = (f * 4 + (quad >> 1)) ^ rx;
        int dc1 = (f * 4 + 2 + (quad >> 1)) ^ rx;
        uint2 lo = *(const uint2*)((const char*)Vts + row * 128 + dc0 * 16 + (quad & 1) * 8);
        uint2 hi = *(const uint2*)((const char*)Vts + row * 128 + dc1 * 16 + (quad & 1) * 8);
        ix4 vv = (ix4){(int)lo.x, (int)lo.y, (int)hi.x, (int)hi.y};
        vf[ht][f] = __builtin_bit_cast(bf16x8, vv);
      }
    }

#pragma unroll
    for (int qi = 0; qi < 2; ++qi) {
      unsigned pw[8];
#pragma unroll
      for (int kt = 0; kt < 4; ++kt) {
        fx4 s = (fx4){0.f, 0.f, 0.f, 0.f};
        s = MFMA16(kf[kt][0], qf[qi][0], s);
        s = MFMA16(kf[kt][1], qf[qi][1], s);
        const float* ma = (const float*)&mqa[kt];
        const float* mc = (const float*)&mqb[kt];
        float p0 = ex2(__builtin_fmaf(s[0], ma[0], mc[0]));
        float p1 = ex2(__builtin_fmaf(s[1], ma[1], mc[1]));
        float p2 = ex2(__builtin_fmaf(s[2], ma[2], mc[2]));
        float p3 = ex2(__builtin_fmaf(s[3], ma[3], mc[3]));
        pw[kt * 2]     = cvtpk(p0, p1);
        pw[kt * 2 + 1] = cvtpk(p2, p3);
      }
      ix4 pi0 = (ix4){(int)pw[0], (int)pw[1], (int)pw[2], (int)pw[3]};
      ix4 pi1 = (ix4){(int)pw[4], (int)pw[5], (int)pw[6], (int)pw[7]};
      bf16x8 pf0 = __builtin_bit_cast(bf16x8, pi0);
      bf16x8 pf1 = __builtin_bit_cast(bf16x8, pi1);
      // row-sum on the MFMA pipe
      sacc[qi] = MFMA16(onesf, pf0, sacc[qi]);
      sacc[qi] = MFMA16(onesf, pf1, sacc[qi]);
#pragma unroll
      for (int ht = 0; ht < 4; ++ht) {
        o[qi][ht] = MFMA16(vf[ht][0], pf0, o[qi][ht]);
        o[qi][ht] = MFMA16(vf[ht][1], pf1, o[qi][ht]);
      }
    }
  }

#pragma unroll
  for (int qi = 0; qi < 2; ++qi) {
    // sacc rows are all identical (ones operand): lane's col l16 sum is in any reg
    float inv = 1.f / fmaxf(sacc[qi][0], 1e-30f);
    int sq = q0 + w * 32 + qi * 16 + l16;
    unsigned short* orow = O + ((size_t)(b * SS + sq)) * DD + h * HDD;
#pragma unroll
    for (int ht = 0; ht < 4; ++ht) {
      uint2 v = make_uint2(pkbf(o[qi][ht][0] * inv, o[qi][ht][1] * inv),
                           pkbf(o[qi][ht][2] * inv, o[qi][ht][3] * inv));
      *(uint2*)&orow[ht * 16 + quad * 4] = v;
    }
  }
}

// ---- LayerNorm over D=768: one WAVE per row, 4 rows/block, no barriers ----
__global__ __launch_bounds__(256) void ln_k(const float* __restrict__ x,
                                            const float* __restrict__ gamma,
                                            const float* __restrict__ beta,
                                            float* __restrict__ out) {
  const int wv = threadIdx.x >> 6, lane = threadIdx.x & 63;
  const int row = blockIdx.x * 4 + wv;
  const float* xr = x + (size_t)row * DD;
  float4 v[3];
  float s = 0.f, ss = 0.f;
#pragma unroll
  for (int j = 0; j < 3; ++j) {
    v[j] = *(const float4*)&xr[j * 256 + lane * 4];
    s += v[j].x + v[j].y + v[j].z + v[j].w;
    ss += v[j].x * v[j].x + v[j].y * v[j].y + v[j].z * v[j].z + v[j].w * v[j].w;
  }
#pragma unroll
  for (int d = 1; d < 64; d <<= 1) {
    s += __shfl_xor(s, d);
    ss += __shfl_xor(ss, d);
  }
  float mu = s * (1.0f / DD);
  float rstd = rsqrtf(ss * (1.0f / DD) - mu * mu + 1e-5f);
  float* orow = out + (size_t)row * DD;
#pragma unroll
  for (int j = 0; j < 3; ++j) {
    float4 g = *(const float4*)&gamma[j * 256 + lane * 4];
    float4 be = *(const float4*)&beta[j * 256 + lane * 4];
    float4 r;
    r.x = (v[j].x - mu) * rstd * g.x + be.x;
    r.y = (v[j].y - mu) * rstd * g.y + be.y;
    r.z = (v[j].z - mu) * rstd * g.z + be.z;
    r.w = (v[j].w - mu) * rstd * g.w + be.w;
    *(float4*)&orow[j * 256 + lane * 4] = r;
  }
}

extern "C" void kernel_launch(void* const* d_in, const int* in_sizes, int n_in,
                              void* d_out, int out_size, void* d_ws, size_t ws_size,
                              hipStream_t stream) {
  (void)in_sizes; (void)n_in; (void)out_size; (void)ws_size;
  const float* ctx   = (const float*)d_in[0];
  const float* mask  = (const float*)d_in[1];
  const float* wqkv  = (const float*)d_in[2];
  const float* wproj = (const float*)d_in[3];
  const float* bproj = (const float*)d_in[4];
  const float* gamma = (const float*)d_in[5];
  const float* beta  = (const float*)d_in[6];
  float* out = (float*)d_out;

  char* p = (char*)d_ws;
  unsigned short* Xbf = (unsigned short*)p; p += (size_t)NEL * 2;
  unsigned short* Qw  = (unsigned short*)p; p += (size_t)NEL * 2;
  unsigned short* Kw  = (unsigned short*)p; p += (size_t)NEL * 2;
  unsigned short* Vtw = (unsigned short*)p; p += (size_t)NEL * 2;
  unsigned short* Ao  = (unsigned short*)p; p += (size_t)NEL * 2;
  unsigned short* WqkvT  = (unsigned short*)p; p += (size_t)DD * NQKV * 2;
  unsigned short* WprojT = (unsigned short*)p; p += (size_t)DD * DD * 2;
  float* xf = (float*)Qw;  // reuse Q+K region (attn done before proj writes)

  prep_k<<<PREP_PACK + PREP_TQKV + PREP_TPROJ, 256, 0, stream>>>(
      ctx, Xbf, wqkv, WqkvT, wproj, WprojT);
  gemm_qkv_k<<<dim3(BS / 128, NQKV / 128), 256, 0, stream>>>(WqkvT, Xbf, Qw, Kw, Vtw);
  attn_k<<<dim3(SS / 128, BB * HH), 256, 0, stream>>>(Qw, Kw, Vtw, mask, Ao);
  gemm_proj_k<<<dim3(BS / 128, DD / 128), 256, 0, stream>>>(WprojT, Ao, ctx, bproj, xf);
  ln_k<<<BS / 4, 256, 0, stream>>>(xf, gamma, beta, out);
}

// Round 12
// 248.333 us; speedup vs baseline: 1.0521x; 1.0014x over previous
//
#include <hip/hip_runtime.h>

// ---- constants for B=4, S=2048, D=768, H=12, HD=64 ----
#define BB 4
#define SS 2048
#define DD 768
#define HH 12
#define HDD 64
#define BS (BB*SS)            // 8192 rows
#define NQKV (3*DD)           // 2304
#define NEL (BS*DD)           // 6291456

typedef __attribute__((ext_vector_type(8))) __bf16 bf16x8;
typedef __attribute__((ext_vector_type(4))) float fx4;
typedef __attribute__((ext_vector_type(4))) int   ix4;

#define MFMA16(a,b,c) __builtin_amdgcn_mfma_f32_16x16x32_bf16((a),(b),(c),0,0,0)

// async global->LDS, 16B per lane, lane-linear dest (wave-uniform base + lane*16)
#define GLLDS(g, l) __builtin_amdgcn_global_load_lds( \
    (const __attribute__((address_space(1))) void*)(g), \
    (__attribute__((address_space(3))) void*)(l), 16, 0, 0)

__device__ __forceinline__ unsigned short f2bf(float f) {
  unsigned u = __builtin_bit_cast(unsigned, f);
  u = (u + 0x7FFFu + ((u >> 16) & 1u)) >> 16;
  return (unsigned short)u;
}
// pack two fp32 -> bf16 pair
__device__ __forceinline__ unsigned pkbf(float a, float b) {
  unsigned ua = __builtin_bit_cast(unsigned, a);
  unsigned ub = __builtin_bit_cast(unsigned, b);
  return ((ua + 0x8000u) >> 16) | ((ub + 0x8000u) & 0xFFFF0000u);
}
// hardware packed fp32->bf16 (RNE), 1 instr for 2 elems
__device__ __forceinline__ unsigned cvtpk(float a, float b) {
  unsigned r;
  asm("v_cvt_pk_bf16_f32 %0, %1, %2" : "=v"(r) : "v"(a), "v"(b));
  return r;
}
__device__ __forceinline__ float ex2(float x) { return __builtin_amdgcn_exp2f(x); }

// ---- fused prep: pack ctx->bf16 + transpose both weight matrices ----
#define PREP_PACK   6144
#define PREP_TQKV   1728   // 72 x 24 tiles
#define PREP_TPROJ  576    // 24 x 24 tiles
__global__ __launch_bounds__(256) void prep_k(const float* __restrict__ ctx,
                                              unsigned short* __restrict__ Xbf,
                                              const float* __restrict__ wqkv,
                                              unsigned short* __restrict__ WqkvT,
                                              const float* __restrict__ wproj,
                                              unsigned short* __restrict__ WprojT) {
  __shared__ unsigned short t[32][33];
  const int bid = blockIdx.x;
  const int tid = threadIdx.x;
  if (bid < PREP_PACK) {
    int i = bid * 256 + tid;
    float4 v = ((const float4*)ctx)[i];
    ((uint2*)Xbf)[i] = make_uint2(pkbf(v.x, v.y), pkbf(v.z, v.w));
    return;
  }
  const float* w; unsigned short* wT; int K, N, bx, by;
  if (bid < PREP_PACK + PREP_TQKV) {
    int tix = bid - PREP_PACK;
    w = wqkv; wT = WqkvT; K = DD; N = NQKV;
    bx = tix % 72; by = tix / 72;
  } else {
    int tix = bid - PREP_PACK - PREP_TQKV;
    w = wproj; wT = WprojT; K = DD; N = DD;
    bx = tix % 24; by = tix / 24;
  }
  int n0 = bx * 32, k0 = by * 32;
  int tx = tid & 31, ty = tid >> 5;
#pragma unroll
  for (int r = ty; r < 32; r += 8)
    t[tx][r] = f2bf(w[(size_t)(k0 + r) * N + n0 + tx]);
  __syncthreads();
#pragma unroll
  for (int r = ty; r < 32; r += 8)
    wT[(size_t)(n0 + r) * K + k0 + tx] = t[r][tx];
}

// XCD-aware block swizzle (requires nwg % 8 == 0; all swizzled grids satisfy)
__device__ __forceinline__ void xcd_swz(int gx, int* bx, int* by) {
  int nwg = gx * gridDim.y;
  int flat = blockIdx.y * gx + blockIdx.x;
  int cpx = nwg >> 3;
  int swz = (flat & 7) * cpx + (flat >> 3);
  *bx = swz % gx;
  *by = swz / gx;
}

// ==== QKV GEMM: C^T[feature][seq] = Wt(2304x768) x X(8192x768)^T ====
// 128x128 tile, BK=32, 3-buffer GLLDS ring (raw s_barrier + counted vmcnt).
// Epilogue: LDS-transpose round-trip -> fully coalesced 128B stores.
__global__ __launch_bounds__(256) void gemm_qkv_k(const unsigned short* __restrict__ Wt,
                                                  const unsigned short* __restrict__ X,
                                                  unsigned short* __restrict__ Qo,
                                                  unsigned short* __restrict__ Ko,
                                                  unsigned short* __restrict__ Vto) {
  __shared__ __align__(16) char smem[49152];
  unsigned short* As = (unsigned short*)smem;            // 3 x 8KB ring
  unsigned short* Bs = (unsigned short*)(smem + 24576);  // 3 x 8KB ring
  const int tid = threadIdx.x;
  const int w = tid >> 6, lane = tid & 63, quad = lane >> 4, l16 = lane & 15;
  int bx, by; xcd_swz(gridDim.x, &bx, &by);
  const int m0 = by << 7;   // feature
  const int n0 = bx << 7;   // seq row
  const int wm = (w & 1) * 64, wn = (w >> 1) * 64;
  fx4 acc[4][4];
#pragma unroll
  for (int i = 0; i < 4; ++i)
#pragma unroll
    for (int c = 0; c < 4; ++c) acc[i][c] = (fx4){0.f, 0.f, 0.f, 0.f};

  const int c0 = tid, c1 = 256 + tid;
  const unsigned short* Ag0 = Wt + (size_t)(m0 + (c0 >> 2)) * DD + (c0 & 3) * 8;
  const unsigned short* Ag1 = Wt + (size_t)(m0 + (c1 >> 2)) * DD + (c1 & 3) * 8;
  const unsigned short* Bg0 = X + (size_t)(n0 + (c0 >> 2)) * DD + (c0 & 3) * 8;
  const unsigned short* Bg1 = X + (size_t)(n0 + (c1 >> 2)) * DD + (c1 & 3) * 8;
  const int wb = w * 1024;   // wave's lane-linear LDS byte base

  // prologue: tiles 0,1 -> bufs 0,1 (FIFO order: t0's 4 loads oldest)
  GLLDS(Ag0, (char*)As + wb);
  GLLDS(Ag1, (char*)As + 4096 + wb);
  GLLDS(Bg0, (char*)Bs + wb);
  GLLDS(Bg1, (char*)Bs + 4096 + wb);
  GLLDS(Ag0 + 32, (char*)As + 8192 + wb);
  GLLDS(Ag1 + 32, (char*)As + 8192 + 4096 + wb);
  GLLDS(Bg0 + 32, (char*)Bs + 8192 + wb);
  GLLDS(Bg1 + 32, (char*)Bs + 8192 + 4096 + wb);
  int cur = 0, wr = 2;

  for (int k0 = 0; k0 < DD; k0 += 32) {
    if (k0 + 32 < DD) {
      asm volatile("s_waitcnt vmcnt(4)" ::: "memory");   // oldest tile landed
    } else {
      asm volatile("s_waitcnt vmcnt(0)" ::: "memory");   // last tile: drain
    }
    __builtin_amdgcn_s_barrier();        // raw: no compiler waitcnt drain
    __builtin_amdgcn_sched_barrier(0);   // pin LDS reads below barrier
    if (k0 + 64 < DD) {                  // issue tile t+2 into buf last read at t-1
      GLLDS(Ag0 + k0 + 64, (char*)As + wr * 8192 + wb);
      GLLDS(Ag1 + k0 + 64, (char*)As + wr * 8192 + 4096 + wb);
      GLLDS(Bg0 + k0 + 64, (char*)Bs + wr * 8192 + wb);
      GLLDS(Bg1 + k0 + 64, (char*)Bs + wr * 8192 + 4096 + wb);
    }
    const unsigned short* Asc = As + cur * 4096;
    const unsigned short* Bsc = Bs + cur * 4096;
    bf16x8 af[4], bf[4];
#pragma unroll
    for (int i = 0; i < 4; ++i) af[i] = *(const bf16x8*)&Asc[(wm + i * 16 + l16) * 32 + quad * 8];
#pragma unroll
    for (int c = 0; c < 4; ++c) bf[c] = *(const bf16x8*)&Bsc[(wn + c * 16 + l16) * 32 + quad * 8];
#pragma unroll
    for (int i = 0; i < 4; ++i)
#pragma unroll
      for (int c = 0; c < 4; ++c) acc[i][c] = MFMA16(af[i], bf[c], acc[i][c]);
    cur = (cur == 2) ? 0 : cur + 1;
    wr  = (wr == 2) ? 0 : wr + 1;
  }

  // ---- epilogue: transpose through LDS scratch (ring is dead now) ----
  unsigned short* t16 = (unsigned short*)smem;   // 128 x 136 x 2B = 34KB
  const int which = m0 / DD;  // block-uniform: 0=Q 1=K 2=V (no 128-tile straddle)
  __syncthreads();            // all waves done with ring reads; vmcnt already 0
#pragma unroll
  for (int i = 0; i < 4; ++i) {
    int fl = wm + i * 16 + quad * 4;
#pragma unroll
    for (int c = 0; c < 4; ++c) {
      int sl = wn + c * 16 + l16;
#pragma unroll
      for (int r = 0; r < 4; ++r) {
        unsigned short v = f2bf(acc[i][c][r]);
        int a = (which == 2) ? (fl + r) * 136 + sl : sl * 136 + (fl + r);
        t16[a] = v;
      }
    }
  }
  __syncthreads();
  const int row2 = tid >> 1, half = tid & 1;      // 128 rows x 2 halves
  const unsigned short* src = t16 + row2 * 136 + half * 64;   // 128B, 16B-aligned
  if (which == 2) {
    int d = m0 - 2 * DD + row2;                   // local feature -> (h, hd)
    int h = d >> 6, hd = d & 63;
    int bq = n0 >> 11, sb = n0 & (SS - 1);
    unsigned short* dst = Vto + ((size_t)(bq * HH + h) * HDD + hd) * SS + sb + half * 64;
#pragma unroll
    for (int j = 0; j < 4; ++j)
      *(ix4*)(dst + j * 8) = *(const ix4*)(src + j * 8);
  } else {
    int srow = n0 + row2;
    int bq = srow >> 11, s = srow & (SS - 1);
    int h = ((m0 - which * DD) >> 6) + half;      // tile spans 2 heads
    unsigned short* base = (which == 0) ? Qo : Ko;
    unsigned short* dst = base + ((size_t)(bq * HH + h) * SS + s) * HDD;
#pragma unroll
    for (int j = 0; j < 4; ++j)
      *(ix4*)(dst + j * 8) = *(const ix4*)(src + j * 8);
  }
}

// ==== proj GEMM: C^T[feat][seq] = WprojT(768x768) x Ao(8192x768)^T ====
// Same 3-buffer counted-vmcnt ring. Epilogue: + b_proj + residual(ctx), fp32 out.
__global__ __launch_bounds__(256) void gemm_proj_k(const unsigned short* __restrict__ Wt,
                                                   const unsigned short* __restrict__ X,
                                                   const float* __restrict__ ctx,
                                                   const float* __restrict__ bproj,
                                                   float* __restrict__ xf) {
  __shared__ unsigned short As[3 * 128 * 32];
  __shared__ unsigned short Bs[3 * 128 * 32];
  const int tid = threadIdx.x;
  const int w = tid >> 6, lane = tid & 63, quad = lane >> 4, l16 = lane & 15;
  int bx, by; xcd_swz(gridDim.x, &bx, &by);
  const int m0 = by << 7;
  const int n0 = bx << 7;
  const int wm = (w & 1) * 64, wn = (w >> 1) * 64;
  fx4 acc[4][4];
#pragma unroll
  for (int i = 0; i < 4; ++i)
#pragma unroll
    for (int c = 0; c < 4; ++c) acc[i][c] = (fx4){0.f, 0.f, 0.f, 0.f};

  const int c0 = tid, c1 = 256 + tid;
  const unsigned short* Ag0 = Wt + (size_t)(m0 + (c0 >> 2)) * DD + (c0 & 3) * 8;
  const unsigned short* Ag1 = Wt + (size_t)(m0 + (c1 >> 2)) * DD + (c1 & 3) * 8;
  const unsigned short* Bg0 = X + (size_t)(n0 + (c0 >> 2)) * DD + (c0 & 3) * 8;
  const unsigned short* Bg1 = X + (size_t)(n0 + (c1 >> 2)) * DD + (c1 & 3) * 8;
  const int wb = w * 1024;

  GLLDS(Ag0, (char*)As + wb);
  GLLDS(Ag1, (char*)As + 4096 + wb);
  GLLDS(Bg0, (char*)Bs + wb);
  GLLDS(Bg1, (char*)Bs + 4096 + wb);
  GLLDS(Ag0 + 32, (char*)As + 8192 + wb);
  GLLDS(Ag1 + 32, (char*)As + 8192 + 4096 + wb);
  GLLDS(Bg0 + 32, (char*)Bs + 8192 + wb);
  GLLDS(Bg1 + 32, (char*)Bs + 8192 + 4096 + wb);
  int cur = 0, wr = 2;

  for (int k0 = 0; k0 < DD; k0 += 32) {
    if (k0 + 32 < DD) {
      asm volatile("s_waitcnt vmcnt(4)" ::: "memory");
    } else {
      asm volatile("s_waitcnt vmcnt(0)" ::: "memory");
    }
    __builtin_amdgcn_s_barrier();
    __builtin_amdgcn_sched_barrier(0);
    if (k0 + 64 < DD) {
      GLLDS(Ag0 + k0 + 64, (char*)As + wr * 8192 + wb);
      GLLDS(Ag1 + k0 + 64, (char*)As + wr * 8192 + 4096 + wb);
      GLLDS(Bg0 + k0 + 64, (char*)Bs + wr * 8192 + wb);
      GLLDS(Bg1 + k0 + 64, (char*)Bs + wr * 8192 + 4096 + wb);
    }
    const unsigned short* Asc = As + cur * 4096;
    const unsigned short* Bsc = Bs + cur * 4096;
    bf16x8 af[4], bf[4];
#pragma unroll
    for (int i = 0; i < 4; ++i) af[i] = *(const bf16x8*)&Asc[(wm + i * 16 + l16) * 32 + quad * 8];
#pragma unroll
    for (int c = 0; c < 4; ++c) bf[c] = *(const bf16x8*)&Bsc[(wn + c * 16 + l16) * 32 + quad * 8];
#pragma unroll
    for (int i = 0; i < 4; ++i)
#pragma unroll
      for (int c = 0; c < 4; ++c) acc[i][c] = MFMA16(af[i], bf[c], acc[i][c]);
    cur = (cur == 2) ? 0 : cur + 1;
    wr  = (wr == 2) ? 0 : wr + 1;
  }

#pragma unroll
  for (int i = 0; i < 4; ++i) {
    int fb = m0 + wm + i * 16 + quad * 4;
    float4 bp = *(const float4*)&bproj[fb];
#pragma unroll
    for (int c = 0; c < 4; ++c) {
      int srow = n0 + wn + c * 16 + l16;
      float4 cx = *(const float4*)&ctx[(size_t)srow * DD + fb];
      float4 r;
      r.x = acc[i][c][0] + bp.x + cx.x;
      r.y = acc[i][c][1] + bp.y + cx.y;
      r.z = acc[i][c][2] + bp.z + cx.z;
      r.w = acc[i][c][3] + bp.w + cx.w;
      *(float4*)&xf[(size_t)srow * DD + fb] = r;
    }
  }
}

// ==== attention: S^T = K·Q^T; P stays in registers (k-permuted PV) ====
// block = 128 q-rows x one (b,h); 4 waves x 32 q-rows; 64-key tiles.
// VERIFIED sync structure (rounds 6/8/10/11: 83.5-85.8us). NEW: XCD-aware
// block swizzle so the 16 q-blocks sharing one (b,h)'s K/V land on the same
// XCD (6 bh/XCD -> 3MB K/V fits 4MB L2) — targets the 2.6x HBM over-fetch.
__global__ __launch_bounds__(256) void attn_k(const unsigned short* __restrict__ Q,
                                              const unsigned short* __restrict__ K,
                                              const unsigned short* __restrict__ Vt,
                                              const float* __restrict__ mask,
                                              unsigned short* __restrict__ O) {
  __shared__ unsigned short Ks[64 * 64];   // [key][dd], 16B chunks XOR-swizzled by row&7
  __shared__ unsigned short Vts[64 * 64];  // [hd][key], same swizzle
  __shared__ float kaS[SS];                // per-key softmax coeff a (8KB)
  __shared__ float kbS[SS];                // per-key softmax coeff b (8KB)
  const int tid = threadIdx.x;
  const int w = tid >> 6, lane = tid & 63;
  const int quad = lane >> 4, l16 = lane & 15;
  // XCD swizzle: 768 blocks, 96/XCD chunk -> consecutive logical blocks
  // (same bh) co-resident on one XCD's L2.
  const int flat = blockIdx.y * gridDim.x + blockIdx.x;
  const int swz = (flat & 7) * 96 + (flat >> 3);
  const int bh = swz >> 4;
  const int q0 = (swz & 15) << 7;
  const int b = bh / HH, h = bh - b * HH;
  const unsigned short* Qb = Q + (size_t)bh * (SS * HDD);
  const unsigned short* Kb = K + (size_t)bh * (SS * HDD);
  const unsigned short* Vtb = Vt + (size_t)bh * (SS * HDD);
  const float* mb = mask + b * SS;

  // one-time: mask -> softmax coeffs, staged to LDS
  //   p = exp2(sc*ka + kb); ka = m*0.125*log2e; kb = (m-1)*1e10*log2e
#pragma unroll
  for (int i = 0; i < 2; ++i) {
    int idx = i * 256 + tid;                        // 512 float4 per table
    float4 mv = ((const float4*)mb)[idx];
    float4 a, c;
    a.x = mv.x * 0.18033688f; a.y = mv.y * 0.18033688f;
    a.z = mv.z * 0.18033688f; a.w = mv.w * 0.18033688f;
    c.x = __builtin_fmaf(mv.x, 1.44269504e10f, -1.44269504e10f);
    c.y = __builtin_fmaf(mv.y, 1.44269504e10f, -1.44269504e10f);
    c.z = __builtin_fmaf(mv.z, 1.44269504e10f, -1.44269504e10f);
    c.w = __builtin_fmaf(mv.w, 1.44269504e10f, -1.44269504e10f);
    ((float4*)kaS)[idx] = a;
    ((float4*)kbS)[idx] = c;
  }

  // Q fragments (B-operand: n=q=l16, k=dd natural)
  bf16x8 qf[2][2];
#pragma unroll
  for (int qi = 0; qi < 2; ++qi)
#pragma unroll
    for (int f = 0; f < 2; ++f)
      qf[qi][f] = *(const bf16x8*)&Qb[(size_t)(q0 + w * 32 + qi * 16 + l16) * HDD + f * 32 + quad * 8];

  fx4 o[2][4];
#pragma unroll
  for (int qi = 0; qi < 2; ++qi)
#pragma unroll
    for (int ht = 0; ht < 4; ++ht) o[qi][ht] = (fx4){0.f, 0.f, 0.f, 0.f};
  fx4 sacc[2];
  sacc[0] = (fx4){0.f, 0.f, 0.f, 0.f};
  sacc[1] = (fx4){0.f, 0.f, 0.f, 0.f};

  // ones fragment for row-sum MFMA (A all 1.0bf16 -> D[m][q] = sum_k P[k][q])
  const ix4 one4 = (ix4){0x3F803F80, 0x3F803F80, 0x3F803F80, 0x3F803F80};
  const bf16x8 onesf = __builtin_bit_cast(bf16x8, one4);

  // staging: 512 chunks of 16B per matrix; 2 per thread; XOR-swizzled placement
  const int cA = tid, cB = 256 + tid;
  const int rA = cA >> 3, pA = (cA & 7) ^ (rA & 7);
  const int rB = cB >> 3, pB = (cB & 7) ^ (rB & 7);

  ix4 rk0 = *(const ix4*)&Kb[(size_t)rA * HDD + pA * 8];
  ix4 rk1 = *(const ix4*)&Kb[(size_t)rB * HDD + pB * 8];
  ix4 rv0 = *(const ix4*)&Vtb[(size_t)rA * SS + pA * 8];
  ix4 rv1 = *(const ix4*)&Vtb[(size_t)rB * SS + pB * 8];

  for (int k0 = 0; k0 < SS; k0 += 64) {
    __syncthreads();
    *(ix4*)((char*)Ks + cA * 16) = rk0;
    *(ix4*)((char*)Ks + cB * 16) = rk1;
    *(ix4*)((char*)Vts + cA * 16) = rv0;
    *(ix4*)((char*)Vts + cB * 16) = rv1;
    __syncthreads();
    if (k0 + 64 < SS) {
      int kn = k0 + 64;
      rk0 = *(const ix4*)&Kb[(size_t)(kn + rA) * HDD + pA * 8];
      rk1 = *(const ix4*)&Kb[(size_t)(kn + rB) * HDD + pB * 8];
      rv0 = *(const ix4*)&Vtb[(size_t)rA * SS + kn + pA * 8];
      rv1 = *(const ix4*)&Vtb[(size_t)rB * SS + kn + pB * 8];
    }

    // mask coefficients from LDS (lgkmcnt only)
    float4 mqa[4], mqb[4];
#pragma unroll
    for (int kt = 0; kt < 4; ++kt) {
      mqa[kt] = *(const float4*)&kaS[k0 + kt * 16 + quad * 4];
      mqb[kt] = *(const float4*)&kbS[k0 + kt * 16 + quad * 4];
    }

    // K fragments (A-operand: m=key=l16, k=dd natural)
    bf16x8 kf[4][2];
#pragma unroll
    for (int kt = 0; kt < 4; ++kt) {
      int row = kt * 16 + l16;
      int rx = row & 7;
#pragma unroll
      for (int f = 0; f < 2; ++f)
        kf[kt][f] = *(const bf16x8*)&Ks[row * 64 + ((f * 4 + quad) ^ rx) * 8];
    }
    // V fragments (A-operand: m=hd=l16, k-permuted: key=f*32+(j>>2)*16+quad*4+(j&3))
    bf16x8 vf[4][2];
#pragma unroll
    for (int ht = 0; ht < 4; ++ht) {
      int row = ht * 16 + l16;
      int rx = row & 7;
#pragma unroll
      for (int f = 0; f < 2; ++f) {
        int dc0 = (f * 4 + (quad >> 1)) ^ rx;
        int dc1 = (f * 4 + 2 + (quad >> 1)) ^ rx;
        uint2 lo = *(const uint2*)((const char*)Vts + row * 128 + dc0 * 16 + (quad & 1) * 8);
        uint2 hi = *(const uint2*)((const char*)Vts + row * 128 + dc1 * 16 + (quad & 1) * 8);
        ix4 vv = (ix4){(int)lo.x, (int)lo.y, (int)hi.x, (int)hi.y};
        vf[ht][f] = __builtin_bit_cast(bf16x8, vv);
      }
    }

#pragma unroll
    for (int qi = 0; qi < 2; ++qi) {
      unsigned pw[8];
#pragma unroll
      for (int kt = 0; kt < 4; ++kt) {
        fx4 s = (fx4){0.f, 0.f, 0.f, 0.f};
        s = MFMA16(kf[kt][0], qf[qi][0], s);
        s = MFMA16(kf[kt][1], qf[qi][1], s);
        const float* ma = (const float*)&mqa[kt];
        const float* mc = (const float*)&mqb[kt];
        float p0 = ex2(__builtin_fmaf(s[0], ma[0], mc[0]));
        float p1 = ex2(__builtin_fmaf(s[1], ma[1], mc[1]));
        float p2 = ex2(__builtin_fmaf(s[2], ma[2], mc[2]));
        float p3 = ex2(__builtin_fmaf(s[3], ma[3], mc[3]));
        pw[kt * 2]     = cvtpk(p0, p1);
        pw[kt * 2 + 1] = cvtpk(p2, p3);
      }
      ix4 pi0 = (ix4){(int)pw[0], (int)pw[1], (int)pw[2], (int)pw[3]};
      ix4 pi1 = (ix4){(int)pw[4], (int)pw[5], (int)pw[6], (int)pw[7]};
      bf16x8 pf0 = __builtin_bit_cast(bf16x8, pi0);
      bf16x8 pf1 = __builtin_bit_cast(bf16x8, pi1);
      // row-sum on the MFMA pipe
      sacc[qi] = MFMA16(onesf, pf0, sacc[qi]);
      sacc[qi] = MFMA16(onesf, pf1, sacc[qi]);
#pragma unroll
      for (int ht = 0; ht < 4; ++ht) {
        o[qi][ht] = MFMA16(vf[ht][0], pf0, o[qi][ht]);
        o[qi][ht] = MFMA16(vf[ht][1], pf1, o[qi][ht]);
      }
    }
  }

#pragma unroll
  for (int qi = 0; qi < 2; ++qi) {
    // sacc rows are all identical (ones operand): lane's col l16 sum is in any reg
    float inv = 1.f / fmaxf(sacc[qi][0], 1e-30f);
    int sq = q0 + w * 32 + qi * 16 + l16;
    unsigned short* orow = O + ((size_t)(b * SS + sq)) * DD + h * HDD;
#pragma unroll
    for (int ht = 0; ht < 4; ++ht) {
      uint2 v = make_uint2(pkbf(o[qi][ht][0] * inv, o[qi][ht][1] * inv),
                           pkbf(o[qi][ht][2] * inv, o[qi][ht][3] * inv));
      *(uint2*)&orow[ht * 16 + quad * 4] = v;
    }
  }
}

// ---- LayerNorm over D=768: one WAVE per row, 4 rows/block, no barriers ----
__global__ __launch_bounds__(256) void ln_k(const float* __restrict__ x,
                                            const float* __restrict__ gamma,
                                            const float* __restrict__ beta,
                                            float* __restrict__ out) {
  const int wv = threadIdx.x >> 6, lane = threadIdx.x & 63;
  const int row = blockIdx.x * 4 + wv;
  const float* xr = x + (size_t)row * DD;
  float4 v[3];
  float s = 0.f, ss = 0.f;
#pragma unroll
  for (int j = 0; j < 3; ++j) {
    v[j] = *(const float4*)&xr[j * 256 + lane * 4];
    s += v[j].x + v[j].y + v[j].z + v[j].w;
    ss += v[j].x * v[j].x + v[j].y * v[j].y + v[j].z * v[j].z + v[j].w * v[j].w;
  }
#pragma unroll
  for (int d = 1; d < 64; d <<= 1) {
    s += __shfl_xor(s, d);
    ss += __shfl_xor(ss, d);
  }
  float mu = s * (1.0f / DD);
  float rstd = rsqrtf(ss * (1.0f / DD) - mu * mu + 1e-5f);
  float* orow = out + (size_t)row * DD;
#pragma unroll
  for (int j = 0; j < 3; ++j) {
    float4 g = *(const float4*)&gamma[j * 256 + lane * 4];
    float4 be = *(const float4*)&beta[j * 256 + lane * 4];
    float4 r;
    r.x = (v[j].x - mu) * rstd * g.x + be.x;
    r.y = (v[j].y - mu) * rstd * g.y + be.y;
    r.z = (v[j].z - mu) * rstd * g.z + be.z;
    r.w = (v[j].w - mu) * rstd * g.w + be.w;
    *(float4*)&orow[j * 256 + lane * 4] = r;
  }
}

extern "C" void kernel_launch(void* const* d_in, const int* in_sizes, int n_in,
                              void* d_out, int out_size, void* d_ws, size_t ws_size,
                              hipStream_t stream) {
  (void)in_sizes; (void)n_in; (void)out_size; (void)ws_size;
  const float* ctx   = (const float*)d_in[0];
  const float* mask  = (const float*)d_in[1];
  const float* wqkv  = (const float*)d_in[2];
  const float* wproj = (const float*)d_in[3];
  const float* bproj = (const float*)d_in[4];
  const float* gamma = (const float*)d_in[5];
  const float* beta  = (const float*)d_in[6];
  float* out = (float*)d_out;

  char* p = (char*)d_ws;
  unsigned short* Xbf = (unsigned short*)p; p += (size_t)NEL * 2;
  unsigned short* Qw  = (unsigned short*)p; p += (size_t)NEL * 2;
  unsigned short* Kw  = (unsigned short*)p; p += (size_t)NEL * 2;
  unsigned short* Vtw = (unsigned short*)p; p += (size_t)NEL * 2;
  unsigned short* Ao  = (unsigned short*)p; p += (size_t)NEL * 2;
  unsigned short* WqkvT  = (unsigned short*)p; p += (size_t)DD * NQKV * 2;
  unsigned short* WprojT = (unsigned short*)p; p += (size_t)DD * DD * 2;
  float* xf = (float*)Qw;  // reuse Q+K region (attn done before proj writes)

  prep_k<<<PREP_PACK + PREP_TQKV + PREP_TPROJ, 256, 0, stream>>>(
      ctx, Xbf, wqkv, WqkvT, wproj, WprojT);
  gemm_qkv_k<<<dim3(BS / 128, NQKV / 128), 256, 0, stream>>>(WqkvT, Xbf, Qw, Kw, Vtw);
  attn_k<<<dim3(SS / 128, BB * HH), 256, 0, stream>>>(Qw, Kw, Vtw, mask, Ao);
  gemm_proj_k<<<dim3(BS / 128, DD / 128), 256, 0, stream>>>(WprojT, Ao, ctx, bproj, xf);
  ln_k<<<BS / 4, 256, 0, stream>>>(xf, gamma, beta, out);
}